// Round 1
// 1496.918 us; speedup vs baseline: 1.0904x; 1.0904x over previous
//
#include <hip/hip_runtime.h>
#include <hip/hip_bf16.h>
#include <cstddef>

#define N_NODES 10000
#define KTOP 30
#define CAP 2048     // max CSR row length
#define NBINS 4096
#define CANDCAP 512
#define NQ4 (N_NODES / 4)   // 2500 float4 per row

typedef _Float16 f16x8 __attribute__((ext_vector_type(8)));
typedef float f32x4 __attribute__((ext_vector_type(4)));

// ---------------- fp32 GEMM: C[M,N] = op(A[M,K] @ B[K,N] + bias) ----------------
template<int RELU, int BIAS>
__global__ __launch_bounds__(256) void gemm_rect(const float* __restrict__ A,
                                                 const float* __restrict__ B,
                                                 const float* __restrict__ bias,
                                                 float* __restrict__ C,
                                                 int M, int N, int K) {
    __shared__ float As[16][132];
    __shared__ float Bs[16][64];
    int t = threadIdx.x;
    int tx = t & 15;
    int ty = t >> 4;
    int m0 = blockIdx.y * 128;
    int n0 = blockIdx.x * 64;
    float acc[8][4];
    for (int r = 0; r < 8; r++) {
        for (int c = 0; c < 4; c++) { acc[r][c] = 0.f; }
    }
    for (int k0 = 0; k0 < K; k0 += 16) {
        for (int i = 0; i < 8; i++) {
            int idx = t + i * 256;
            int m = idx >> 4;
            int k = idx & 15;
            int gm = m0 + m;
            float v = 0.f;
            if (gm < M) { v = A[(size_t)gm * K + k0 + k]; }
            As[k][m] = v;
        }
        for (int i = 0; i < 4; i++) {
            int idx = t + i * 256;
            int k = idx >> 6;
            int n = idx & 63;
            int gn = n0 + n;
            float v = 0.f;
            if (gn < N) { v = B[(size_t)(k0 + k) * N + gn]; }
            Bs[k][n] = v;
        }
        __syncthreads();
        for (int kk = 0; kk < 16; kk++) {
            float a[8];
            float b[4];
            #pragma unroll
            for (int r = 0; r < 8; r++) { a[r] = As[kk][ty * 8 + r]; }
            #pragma unroll
            for (int c = 0; c < 4; c++) { b[c] = Bs[kk][tx * 4 + c]; }
            #pragma unroll
            for (int r = 0; r < 8; r++) {
                #pragma unroll
                for (int c = 0; c < 4; c++) {
                    acc[r][c] = fmaf(a[r], b[c], acc[r][c]);
                }
            }
        }
        __syncthreads();
    }
    for (int r = 0; r < 8; r++) {
        int gm = m0 + ty * 8 + r;
        if (gm >= M) { continue; }
        for (int c = 0; c < 4; c++) {
            int gn = n0 + tx * 4 + c;
            if (gn >= N) { continue; }
            float v = acc[r][c];
            if (BIAS) { v += bias[gn]; }
            if (RELU) { v = fmaxf(v, 0.f); }
            C[(size_t)gm * N + gn] = v;
        }
    }
}

// ---------------- row normalize, numpy-pairwise-exact semantics ----------------
// Also emits the scaled fp16 2-way split of hn (hi + lo), scaled by 2^8 to keep
// all components in the fp16 normal range. Used by the MFMA S-GEMM.
__global__ __launch_bounds__(256) void rownorm_np_kernel(float* __restrict__ h,
                                                         _Float16* __restrict__ hhi,
                                                         _Float16* __restrict__ hlo) {
    __shared__ float row[256];
    __shared__ float denom_sh;
    int r = blockIdx.x;
    int t = threadIdx.x;
    float* p = h + (size_t)r * 256;
    row[t] = p[t];
    __syncthreads();
    if (t == 0) {
        float res[2];
        for (int half = 0; half < 2; half++) {
            const float* a = row + half * 128;
            float rr[8];
            #pragma unroll
            for (int j = 0; j < 8; j++) {
                rr[j] = __fmul_rn(a[j], a[j]);
            }
            for (int i = 8; i < 128; i += 8) {
                #pragma unroll
                for (int j = 0; j < 8; j++) {
                    rr[j] = __fadd_rn(rr[j], __fmul_rn(a[i + j], a[i + j]));
                }
            }
            res[half] = __fadd_rn(
                __fadd_rn(__fadd_rn(rr[0], rr[1]), __fadd_rn(rr[2], rr[3])),
                __fadd_rn(__fadd_rn(rr[4], rr[5]), __fadd_rn(rr[6], rr[7])));
        }
        float tot = __fadd_rn(res[0], res[1]);
        denom_sh = __fadd_rn(__fsqrt_rn(tot), 1e-8f);
    }
    __syncthreads();
    float v = __fdiv_rn(row[t], denom_sh);
    p[t] = v;
    float sc = v * 256.0f;                 // exact (power-of-2 scale)
    _Float16 hv = (_Float16)sc;            // RNE to fp16
    float rem = sc - (float)hv;            // exact (Sterbenz-range)
    hhi[(size_t)r * 256 + t] = hv;
    hlo[(size_t)r * 256 + t] = (_Float16)rem;
}

// ---------------- S tile GEMM via fp16-split MFMA ----------------
// S[r,c] = relu(hn[r].hn[c]) computed as (Ah+Al)(Bh+Bl) ~= AhBh + AhBl + AlBh
// on v_mfma_f32_16x16x32_f16; error terms are all <= ~3*2^-24 per product,
// below the fp32 accumulation noise the previous (passing) fp32 kernel had.
// Operands pre-scaled by 2^8 each; epilogue multiplies by 2^-16 (exact).
__device__ __forceinline__ void gload16(const void* g, void* l) {
    __builtin_amdgcn_global_load_lds(
        (const __attribute__((address_space(1))) unsigned int*)g,
        (__attribute__((address_space(3))) unsigned int*)l, 16, 0, 0);
}

__global__ __launch_bounds__(256) void gemm_s_f16(const _Float16* __restrict__ hi,
                                                  const _Float16* __restrict__ lo,
                                                  float* __restrict__ S) {
    int rb = blockIdx.y * 128;
    int cb = blockIdx.x * 128;
    if (cb < rb) { return; }
    // 4 tiles of [128 rows][64 halves] = 16 KB each: Ahi, Alo, Bhi, Blo.
    // LDS layout linear (global_load_lds writes base + lane*16); the k-slot
    // XOR swizzle (slot ^ (row&7)) is applied on the GLOBAL source address and
    // un-applied on the ds_read side (both-sides-or-neither rule).
    __shared__ __align__(16) unsigned short Hs[32768];  // 64 KB
    int t = threadIdx.x;
    int w = t >> 6;
    int lane = t & 63;
    int wr = w >> 1, wc = w & 1;          // wave -> 64x64 quadrant
    int lrow = lane & 15, lk = lane >> 4; // mfma A/B fragment mapping
    int lr8 = lane >> 3, ls8 = lane & 7;  // staging: 8 rows x 8 slots per 1KB chunk
    int koffb = ((ls8 ^ lr8) << 4);       // pre-swizzled 16B slot in global row

    f32x4 acc[4][4];
    #pragma unroll
    for (int i = 0; i < 4; i++) {
        #pragma unroll
        for (int j = 0; j < 4; j++) {
            f32x4 z = {0.f, 0.f, 0.f, 0.f};
            acc[i][j] = z;
        }
    }

    const char* hp = (const char*)hi;
    const char* lp = (const char*)lo;

    #pragma unroll 1
    for (int ks = 0; ks < 4; ks++) {
        int k0b = ks * 128;  // byte offset into a 512-B row
        #pragma unroll
        for (int tt = 0; tt < 4; tt++) {
            int c = w * 4 + tt;            // chunk 0..15, 8 rows each
            int rowloc = c * 8 + lr8;
            int na = rb + rowloc; if (na > N_NODES - 1) { na = N_NODES - 1; }
            int nb = cb + rowloc; if (nb > N_NODES - 1) { nb = N_NODES - 1; }
            size_t offA = (size_t)na * 512 + k0b + koffb;
            size_t offB = (size_t)nb * 512 + k0b + koffb;
            gload16(hp + offA, &Hs[0     + c * 512]);
            gload16(lp + offA, &Hs[8192  + c * 512]);
            gload16(hp + offB, &Hs[16384 + c * 512]);
            gload16(lp + offB, &Hs[24576 + c * 512]);
        }
        __builtin_amdgcn_s_waitcnt(0);
        __syncthreads();
        #pragma unroll 1
        for (int kk = 0; kk < 2; kk++) {
            f16x8 ah[4], al[4], bh[4], bl[4];
            #pragma unroll
            for (int i = 0; i < 4; i++) {
                int ar = wr * 64 + i * 16 + lrow;
                int br = wc * 64 + i * 16 + lrow;
                int ps = ((kk * 4 + lk) ^ (lrow & 7)) * 8;  // halves
                ah[i] = *(const f16x8*)&Hs[0     + ar * 64 + ps];
                al[i] = *(const f16x8*)&Hs[8192  + ar * 64 + ps];
                bh[i] = *(const f16x8*)&Hs[16384 + br * 64 + ps];
                bl[i] = *(const f16x8*)&Hs[24576 + br * 64 + ps];
            }
            #pragma unroll
            for (int i = 0; i < 4; i++) {
                #pragma unroll
                for (int j = 0; j < 4; j++) {
                    acc[i][j] = __builtin_amdgcn_mfma_f32_16x16x32_f16(ah[i], bh[j], acc[i][j], 0, 0, 0);
                    acc[i][j] = __builtin_amdgcn_mfma_f32_16x16x32_f16(ah[i], bl[j], acc[i][j], 0, 0, 0);
                    acc[i][j] = __builtin_amdgcn_mfma_f32_16x16x32_f16(al[i], bh[j], acc[i][j], 0, 0, 0);
                }
            }
        }
        __syncthreads();
    }

    // epilogue: C/D frag layout col = lane&15, row = (lane>>4)*4 + reg.
    const float inv = 1.0f / 65536.0f;  // undo 2^8 * 2^8 operand scaling (exact)
    #pragma unroll
    for (int i = 0; i < 4; i++) {
        int rrb = rb + wr * 64 + i * 16 + lk * 4;
        #pragma unroll
        for (int j = 0; j < 4; j++) {
            int cc = cb + wc * 64 + j * 16 + lrow;
            if (cc >= N_NODES) { continue; }
            #pragma unroll
            for (int q = 0; q < 4; q++) {
                int rr = rrb + q;
                if (rr >= N_NODES) { continue; }
                float v = fmaxf(acc[i][j][q] * inv, 0.f);
                S[(size_t)rr * N_NODES + cc] = v;
                S[(size_t)cc * N_NODES + rr] = v;  // mirror (bit-identical dot)
            }
        }
    }
}

// ---------------- radix-select top-30 per row, ties -> HIGHEST index ----------------
__global__ __launch_bounds__(256) void topk_radix_kernel(float* __restrict__ S,
                                                         float* __restrict__ tv,
                                                         int* __restrict__ ti) {
    __shared__ int hist[NBINS];
    __shared__ int chunkSum[64];
    __shared__ float cv[CANDCAP];
    __shared__ int ci[CANDCAP];
    __shared__ int cntSh;
    __shared__ int thrSh;
    __shared__ float wv[4];
    __shared__ int wi[4];
    int t = threadIdx.x;
    int r = blockIdx.x;
    float* row = S + (size_t)r * N_NODES;

    for (int b = t; b < NBINS; b += 256) { hist[b] = 0; }
    if (t == 0) { cntSh = 0; }
    __syncthreads();

    // pass 1: histogram of positives (all waves), 10-deep strided loads
    {
        float4 vv[10];
        int ok[10];
        #pragma unroll
        for (int u = 0; u < 10; u++) {
            int j4 = t + u * 256;
            ok[u] = j4 < NQ4;
            int jc = ok[u] ? j4 : (NQ4 - 1);
            vv[u] = *(const float4*)(row + 4 * jc);
        }
        #pragma unroll
        for (int u = 0; u < 10; u++) {
            if (!ok[u]) { continue; }
            float4 v = vv[u];
            if (v.x > 0.f) { atomicAdd(&hist[__float_as_uint(v.x) >> 18], 1); }
            if (v.y > 0.f) { atomicAdd(&hist[__float_as_uint(v.y) >> 18], 1); }
            if (v.z > 0.f) { atomicAdd(&hist[__float_as_uint(v.z) >> 18], 1); }
            if (v.w > 0.f) { atomicAdd(&hist[__float_as_uint(v.w) >> 18], 1); }
        }
    }
    __syncthreads();

    // threshold scan: wave 0 only, wave-synchronous
    if (t < 64) {
        int cs = 0;
        for (int b = 0; b < 64; b++) { cs += hist[t * 64 + b]; }
        chunkSum[t] = cs;
        if (t == 0) {
            int npos = 0;
            for (int c = 0; c < 64; c++) { npos += chunkSum[c]; }
            if (npos < KTOP) {
                thrSh = -1;  // fallback
            } else {
                int cum = 0;
                int c = 63;
                for (; c >= 0; c--) {
                    cum += chunkSum[c];
                    if (cum >= KTOP) { break; }
                }
                int acc = cum - chunkSum[c];
                int T = c * 64;
                for (int b = c * 64 + 63; b >= c * 64; b--) {
                    acc += hist[b];
                    if (acc >= KTOP) { T = b; break; }
                }
                thrSh = T;
            }
        }
    }
    __syncthreads();
    int T = thrSh;

    if (T >= 0) {
        // pass 2: collect candidates (positive, key >= T); all waves, L2-warm
        float4 vv[10];
        int ok[10];
        #pragma unroll
        for (int u = 0; u < 10; u++) {
            int j4 = t + u * 256;
            ok[u] = j4 < NQ4;
            int jc = ok[u] ? j4 : (NQ4 - 1);
            vv[u] = *(const float4*)(row + 4 * jc);
        }
        #pragma unroll
        for (int u = 0; u < 10; u++) {
            if (!ok[u]) { continue; }
            float4 v = vv[u];
            int base = 4 * (t + u * 256);
            float vq[4];
            vq[0] = v.x; vq[1] = v.y; vq[2] = v.z; vq[3] = v.w;
            #pragma unroll
            for (int q = 0; q < 4; q++) {
                if (vq[q] > 0.f && (int)(__float_as_uint(vq[q]) >> 18) >= T) {
                    int p = atomicAdd(&cntSh, 1);
                    if (p < CANDCAP) {
                        cv[p] = vq[q];
                        ci[p] = base + q;
                    }
                }
            }
        }
    }
    __syncthreads();
    int ncand = cntSh;

    if (T < 0 || ncand > CANDCAP) {
        // exact fallback: block-wide iterative argmax over the global row
        for (int k = 0; k < KTOP; k++) {
            float bv = -1.f;
            int bi = -1;
            for (int j = t; j < N_NODES; j += 256) {
                float v = row[j];
                if (v >= bv) { bv = v; bi = j; }
            }
            for (int off = 32; off > 0; off >>= 1) {
                float ov = __shfl_down(bv, off, 64);
                int oi = __shfl_down(bi, off, 64);
                if (ov > bv || (ov == bv && oi > bi)) { bv = ov; bi = oi; }
            }
            if ((t & 63) == 0) { wv[t >> 6] = bv; wi[t >> 6] = bi; }
            __syncthreads();
            if (t == 0) {
                float fv = wv[0];
                int fi = wi[0];
                for (int q = 1; q < 4; q++) {
                    if (wv[q] > fv || (wv[q] == fv && wi[q] > fi)) { fv = wv[q]; fi = wi[q]; }
                }
                tv[r * KTOP + k] = fv;
                ti[r * KTOP + k] = fi;
                row[fi] = -1.f;
            }
            __syncthreads();
        }
        return;
    }

    // selection: wave 0 only, barrier-free; (value desc, index desc)
    if (t < 64) {
        for (int k = 0; k < KTOP; k++) {
            float bv = -2.f;
            int bi = -1;
            int bq = -1;
            for (int q = t; q < ncand; q += 64) {
                float v = cv[q];
                int idx = ci[q];
                if (v > bv || (v == bv && idx > bi)) { bv = v; bi = idx; bq = q; }
            }
            for (int m = 32; m > 0; m >>= 1) {
                float ov = __shfl_xor(bv, m, 64);
                int oi = __shfl_xor(bi, m, 64);
                int oq = __shfl_xor(bq, m, 64);
                if (ov > bv || (ov == bv && oi > bi)) { bv = ov; bi = oi; bq = oq; }
            }
            // all lanes agree on winner
            if (t == 0) {
                tv[r * KTOP + k] = bv;
                ti[r * KTOP + k] = bi;
                cv[bq] = -2.f;
            }
        }
    }
}

// ---------------- degree accumulation ----------------
__global__ __launch_bounds__(256) void degree_kernel(const float* __restrict__ tv,
                                                     const int* __restrict__ ti,
                                                     float* __restrict__ deg) {
    int e = blockIdx.x * 256 + threadIdx.x;
    if (e >= N_NODES * KTOP) { return; }
    int i = e / KTOP;
    int j = ti[e];
    float v = 0.5f * tv[e];
    atomicAdd(deg + i, v);
    atomicAdd(deg + j, v);
}

__global__ __launch_bounds__(256) void dis_kernel(const float* __restrict__ deg,
                                                  float* __restrict__ dis) {
    int i = blockIdx.x * 256 + threadIdx.x;
    if (i < N_NODES) {
        float d = deg[i];
        dis[i] = d > 0.f ? 1.f / sqrtf(fmaxf(d, 1e-8f)) : 0.f;
    }
}

// ---------------- CSR build ----------------
__global__ __launch_bounds__(256) void csr_build(const float* __restrict__ tv,
                                                 const int* __restrict__ ti,
                                                 const float* __restrict__ dis,
                                                 int* __restrict__ cnt,
                                                 int* __restrict__ nbr,
                                                 float* __restrict__ wgt) {
    int e = blockIdx.x * 256 + threadIdx.x;
    if (e >= N_NODES * KTOP) { return; }
    int i = e / KTOP;
    int j = ti[e];
    float v = tv[e];
    float vrev = 0.f;
    bool mutual = false;
    const int* tj = ti + (size_t)j * KTOP;
    const float* tvj = tv + (size_t)j * KTOP;
    for (int k = 0; k < KTOP; k++) {
        if (tj[k] == i) { vrev = tvj[k]; mutual = true; }
    }
    float w = 0.5f * (v + vrev) * dis[i] * dis[j];
    int p = atomicAdd(cnt + i, 1);
    if (p < CAP) {
        nbr[(size_t)i * CAP + p] = j;
        wgt[(size_t)i * CAP + p] = w;
    }
    if (!mutual) {
        int p2 = atomicAdd(cnt + j, 1);
        if (p2 < CAP) {
            nbr[(size_t)j * CAP + p2] = i;
            wgt[(size_t)j * CAP + p2] = w;
        }
    }
}

// ---------------- gather SpMM, 128 channels, relu fused ----------------
__global__ __launch_bounds__(256) void gather128(const int* __restrict__ cnt,
                                                 const int* __restrict__ nbr,
                                                 const float* __restrict__ wgt,
                                                 const float* __restrict__ T,
                                                 float* __restrict__ Y) {
    int node = blockIdx.x * 2 + (threadIdx.x >> 7);
    int c = threadIdx.x & 127;
    if (node >= N_NODES) { return; }
    int n = cnt[node];
    if (n > CAP) { n = CAP; }
    const int* nb = nbr + (size_t)node * CAP;
    const float* wg = wgt + (size_t)node * CAP;
    float acc = 0.f;
    for (int k = 0; k < n; k++) {
        acc = fmaf(wg[k], T[(size_t)nb[k] * 128 + c], acc);
    }
    Y[(size_t)node * 128 + c] = fmaxf(acc, 0.f);
}

// ---------------- gather SpMM, 16 channels ----------------
__global__ __launch_bounds__(256) void gather16(const int* __restrict__ cnt,
                                                const int* __restrict__ nbr,
                                                const float* __restrict__ wgt,
                                                const float* __restrict__ T,
                                                float* __restrict__ Y) {
    int node = blockIdx.x * 16 + (threadIdx.x >> 4);
    int c = threadIdx.x & 15;
    if (node >= N_NODES) { return; }
    int n = cnt[node];
    if (n > CAP) { n = CAP; }
    const int* nb = nbr + (size_t)node * CAP;
    const float* wg = wgt + (size_t)node * CAP;
    float acc = 0.f;
    for (int k = 0; k < n; k++) {
        acc = fmaf(wg[k], T[(size_t)nb[k] * 16 + c], acc);
    }
    Y[(size_t)node * 16 + c] = acc;
}

// ---------------- Adj scatter (dense output) ----------------
__global__ __launch_bounds__(256) void adj_scatter(const float* __restrict__ tv,
                                                   const int* __restrict__ ti,
                                                   const float* __restrict__ dis,
                                                   float* __restrict__ Adj) {
    int e = blockIdx.x * 256 + threadIdx.x;
    if (e >= N_NODES * KTOP) { return; }
    int i = e / KTOP;
    int j = ti[e];
    float v = tv[e];
    float vrev = 0.f;
    const int* tj = ti + (size_t)j * KTOP;
    const float* tvj = tv + (size_t)j * KTOP;
    for (int k = 0; k < KTOP; k++) {
        if (tj[k] == i) { vrev = tvj[k]; }
    }
    float w = 0.5f * (v + vrev) * dis[i] * dis[j];
    Adj[(size_t)i * N_NODES + j] = w;
    Adj[(size_t)j * N_NODES + i] = w;
}

extern "C" void kernel_launch(void* const* d_in, const int* in_sizes, int n_in,
                              void* d_out, int out_size, void* d_ws, size_t ws_size,
                              hipStream_t stream) {
    const float* features = (const float*)d_in[0];
    const float* x   = (const float*)d_in[1];
    const float* W1  = (const float*)d_in[2];
    const float* W2  = (const float*)d_in[3];
    const float* Wg1 = (const float*)d_in[4];
    const float* bg1 = (const float*)d_in[5];
    const float* Wg2 = (const float*)d_in[6];
    const float* bg2 = (const float*)d_in[7];

    float* ws = (float*)d_ws;
    float* hbuf = ws;                         // 2,560,000 f
    float* htmp = ws + 2560000;               // 2,560,000 f
    float* tv   = ws + 5120000;               // 300,000 f
    int*   ti   = (int*)(ws + 5420000);       // 300,000 i
    float* deg  = ws + 5720000;               // 10,000 f
    float* dis  = ws + 5730000;               // 10,000 f
    float* t2   = ws + 5740000;               // 160,000 f
    int*   cnt  = (int*)(ws + 5900000);       // 10,000 i
    float* t1   = hbuf;                       // reuse
    float* y1   = htmp;                       // reuse (after gemm_s consumed hi/lo)

    // fp16 split of hn lives in the dead htmp region (h1 is dead after W2 GEMM):
    // Hhi: 2.56M halves = 5.12 MB, Hlo: same. Both dead once gemm_s_f16 is done.
    _Float16* Hhi = (_Float16*)(ws + 2560000);
    _Float16* Hlo = Hhi + 2560000;

    float* out_f = (float*)d_out;             // 160,000 f32
    float* Adj   = out_f + 160000;            // 1e8 f32 = 400 MB
    float* Sbuf  = Adj;                       // S until topk
    int*   nbr   = (int*)Adj;                 // CSR neighbors 82 MB
    float* wgt   = (float*)(Adj + (size_t)N_NODES * CAP);  // CSR weights 82 MB

    // ---- fp32 MLP chain ----
    dim3 g1(4, 79);
    gemm_rect<1, 0><<<g1, dim3(256), 0, stream>>>(
        features, W1, (const float*)nullptr, htmp, N_NODES, 256, 256);
    gemm_rect<0, 0><<<g1, dim3(256), 0, stream>>>(
        htmp, W2, (const float*)nullptr, hbuf, N_NODES, 256, 256);
    rownorm_np_kernel<<<dim3(N_NODES), dim3(256), 0, stream>>>(hbuf, Hhi, Hlo);

    // ---- S (triangle + mirror) via fp16-split MFMA, radix top-30 ----
    gemm_s_f16<<<dim3(79, 79), dim3(256), 0, stream>>>(Hhi, Hlo, Sbuf);
    topk_radix_kernel<<<dim3(N_NODES), dim3(256), 0, stream>>>(Sbuf, tv, ti);

    // ---- degrees + normalization ----
    hipMemsetAsync(deg, 0, N_NODES * sizeof(float), stream);
    int eblocks = (N_NODES * KTOP + 255) / 256;
    degree_kernel<<<dim3(eblocks), dim3(256), 0, stream>>>(tv, ti, deg);
    dis_kernel<<<dim3((N_NODES + 255) / 256), dim3(256), 0, stream>>>(deg, dis);

    // ---- CSR build in the (dead) S/Adj region ----
    hipMemsetAsync(cnt, 0, N_NODES * sizeof(int), stream);
    csr_build<<<dim3(eblocks), dim3(256), 0, stream>>>(tv, ti, dis, cnt, nbr, wgt);

    // ---- GCN layers via gather SpMM ----
    gemm_rect<0, 1><<<dim3(2, 79), dim3(256), 0, stream>>>(
        x, Wg1, bg1, t1, N_NODES, 128, 256);
    gather128<<<dim3(N_NODES / 2), dim3(256), 0, stream>>>(cnt, nbr, wgt, t1, y1);
    gemm_rect<0, 1><<<dim3(1, 79), dim3(256), 0, stream>>>(
        y1, Wg2, bg2, t2, N_NODES, 16, 128);
    gather16<<<dim3((N_NODES + 15) / 16), dim3(256), 0, stream>>>(cnt, nbr, wgt, t2, out_f);

    // ---- dense Adj output last (overwrites CSR region) ----
    hipMemsetAsync(Adj, 0, (size_t)N_NODES * N_NODES * sizeof(float), stream);
    adj_scatter<<<dim3(eblocks), dim3(256), 0, stream>>>(tv, ti, dis, Adj);
}

// Round 2
// 1443.172 us; speedup vs baseline: 1.1310x; 1.0372x over previous
//
#include <hip/hip_runtime.h>
#include <hip/hip_bf16.h>
#include <cstddef>

#define N_NODES 10000
#define KTOP 30
#define CAP 2048     // max CSR row length
#define NBINS 4096
#define CANDCAP 512
#define NQ4 (N_NODES / 4)   // 2500 float4 per row

typedef _Float16 f16x8 __attribute__((ext_vector_type(8)));
typedef float f32x4 __attribute__((ext_vector_type(4)));

// ---------------- fp32 GEMM: C[M,N] = op(A[M,K] @ B[K,N] + bias) ----------------
template<int RELU, int BIAS>
__global__ __launch_bounds__(256) void gemm_rect(const float* __restrict__ A,
                                                 const float* __restrict__ B,
                                                 const float* __restrict__ bias,
                                                 float* __restrict__ C,
                                                 int M, int N, int K) {
    __shared__ float As[16][132];
    __shared__ float Bs[16][64];
    int t = threadIdx.x;
    int tx = t & 15;
    int ty = t >> 4;
    int m0 = blockIdx.y * 128;
    int n0 = blockIdx.x * 64;
    float acc[8][4];
    for (int r = 0; r < 8; r++) {
        for (int c = 0; c < 4; c++) { acc[r][c] = 0.f; }
    }
    for (int k0 = 0; k0 < K; k0 += 16) {
        for (int i = 0; i < 8; i++) {
            int idx = t + i * 256;
            int m = idx >> 4;
            int k = idx & 15;
            int gm = m0 + m;
            float v = 0.f;
            if (gm < M) { v = A[(size_t)gm * K + k0 + k]; }
            As[k][m] = v;
        }
        for (int i = 0; i < 4; i++) {
            int idx = t + i * 256;
            int k = idx >> 6;
            int n = idx & 63;
            int gn = n0 + n;
            float v = 0.f;
            if (gn < N) { v = B[(size_t)(k0 + k) * N + gn]; }
            Bs[k][n] = v;
        }
        __syncthreads();
        for (int kk = 0; kk < 16; kk++) {
            float a[8];
            float b[4];
            #pragma unroll
            for (int r = 0; r < 8; r++) { a[r] = As[kk][ty * 8 + r]; }
            #pragma unroll
            for (int c = 0; c < 4; c++) { b[c] = Bs[kk][tx * 4 + c]; }
            #pragma unroll
            for (int r = 0; r < 8; r++) {
                #pragma unroll
                for (int c = 0; c < 4; c++) {
                    acc[r][c] = fmaf(a[r], b[c], acc[r][c]);
                }
            }
        }
        __syncthreads();
    }
    for (int r = 0; r < 8; r++) {
        int gm = m0 + ty * 8 + r;
        if (gm >= M) { continue; }
        for (int c = 0; c < 4; c++) {
            int gn = n0 + tx * 4 + c;
            if (gn >= N) { continue; }
            float v = acc[r][c];
            if (BIAS) { v += bias[gn]; }
            if (RELU) { v = fmaxf(v, 0.f); }
            C[(size_t)gm * N + gn] = v;
        }
    }
}

// ---------------- row normalize, numpy-pairwise-exact semantics ----------------
__global__ __launch_bounds__(256) void rownorm_np_kernel(float* __restrict__ h,
                                                         _Float16* __restrict__ hhi,
                                                         _Float16* __restrict__ hlo) {
    __shared__ float row[256];
    __shared__ float denom_sh;
    int r = blockIdx.x;
    int t = threadIdx.x;
    float* p = h + (size_t)r * 256;
    row[t] = p[t];
    __syncthreads();
    if (t == 0) {
        float res[2];
        for (int half = 0; half < 2; half++) {
            const float* a = row + half * 128;
            float rr[8];
            #pragma unroll
            for (int j = 0; j < 8; j++) {
                rr[j] = __fmul_rn(a[j], a[j]);
            }
            for (int i = 8; i < 128; i += 8) {
                #pragma unroll
                for (int j = 0; j < 8; j++) {
                    rr[j] = __fadd_rn(rr[j], __fmul_rn(a[i + j], a[i + j]));
                }
            }
            res[half] = __fadd_rn(
                __fadd_rn(__fadd_rn(rr[0], rr[1]), __fadd_rn(rr[2], rr[3])),
                __fadd_rn(__fadd_rn(rr[4], rr[5]), __fadd_rn(rr[6], rr[7])));
        }
        float tot = __fadd_rn(res[0], res[1]);
        denom_sh = __fadd_rn(__fsqrt_rn(tot), 1e-8f);
    }
    __syncthreads();
    float v = __fdiv_rn(row[t], denom_sh);
    p[t] = v;
    float sc = v * 256.0f;                 // exact (power-of-2 scale)
    _Float16 hv = (_Float16)sc;            // RNE to fp16
    float rem = sc - (float)hv;            // exact (Sterbenz-range)
    hhi[(size_t)r * 256 + t] = hv;
    hlo[(size_t)r * 256 + t] = (_Float16)rem;
}

// ---------------- S tile GEMM via fp16-split MFMA ----------------
__device__ __forceinline__ void gload16(const void* g, void* l) {
    __builtin_amdgcn_global_load_lds(
        (const __attribute__((address_space(1))) unsigned int*)g,
        (__attribute__((address_space(3))) unsigned int*)l, 16, 0, 0);
}

__global__ __launch_bounds__(256) void gemm_s_f16(const _Float16* __restrict__ hi,
                                                  const _Float16* __restrict__ lo,
                                                  float* __restrict__ S) {
    int rb = blockIdx.y * 128;
    int cb = blockIdx.x * 128;
    if (cb < rb) { return; }
    __shared__ __align__(16) unsigned short Hs[32768];  // 64 KB
    int t = threadIdx.x;
    int w = t >> 6;
    int lane = t & 63;
    int wr = w >> 1, wc = w & 1;          // wave -> 64x64 quadrant
    int lrow = lane & 15, lk = lane >> 4; // mfma A/B fragment mapping
    int lr8 = lane >> 3, ls8 = lane & 7;  // staging: 8 rows x 8 slots per 1KB chunk
    int koffb = ((ls8 ^ lr8) << 4);       // pre-swizzled 16B slot in global row

    f32x4 acc[4][4];
    #pragma unroll
    for (int i = 0; i < 4; i++) {
        #pragma unroll
        for (int j = 0; j < 4; j++) {
            f32x4 z = {0.f, 0.f, 0.f, 0.f};
            acc[i][j] = z;
        }
    }

    const char* hp = (const char*)hi;
    const char* lp = (const char*)lo;

    #pragma unroll 1
    for (int ks = 0; ks < 4; ks++) {
        int k0b = ks * 128;  // byte offset into a 512-B row
        #pragma unroll
        for (int tt = 0; tt < 4; tt++) {
            int c = w * 4 + tt;            // chunk 0..15, 8 rows each
            int rowloc = c * 8 + lr8;
            int na = rb + rowloc; if (na > N_NODES - 1) { na = N_NODES - 1; }
            int nb = cb + rowloc; if (nb > N_NODES - 1) { nb = N_NODES - 1; }
            size_t offA = (size_t)na * 512 + k0b + koffb;
            size_t offB = (size_t)nb * 512 + k0b + koffb;
            gload16(hp + offA, &Hs[0     + c * 512]);
            gload16(lp + offA, &Hs[8192  + c * 512]);
            gload16(hp + offB, &Hs[16384 + c * 512]);
            gload16(lp + offB, &Hs[24576 + c * 512]);
        }
        __builtin_amdgcn_s_waitcnt(0);
        __syncthreads();
        #pragma unroll 1
        for (int kk = 0; kk < 2; kk++) {
            f16x8 ah[4], al[4], bh[4], bl[4];
            #pragma unroll
            for (int i = 0; i < 4; i++) {
                int ar = wr * 64 + i * 16 + lrow;
                int br = wc * 64 + i * 16 + lrow;
                int ps = ((kk * 4 + lk) ^ (lrow & 7)) * 8;  // halves
                ah[i] = *(const f16x8*)&Hs[0     + ar * 64 + ps];
                al[i] = *(const f16x8*)&Hs[8192  + ar * 64 + ps];
                bh[i] = *(const f16x8*)&Hs[16384 + br * 64 + ps];
                bl[i] = *(const f16x8*)&Hs[24576 + br * 64 + ps];
            }
            #pragma unroll
            for (int i = 0; i < 4; i++) {
                #pragma unroll
                for (int j = 0; j < 4; j++) {
                    acc[i][j] = __builtin_amdgcn_mfma_f32_16x16x32_f16(ah[i], bh[j], acc[i][j], 0, 0, 0);
                    acc[i][j] = __builtin_amdgcn_mfma_f32_16x16x32_f16(ah[i], bl[j], acc[i][j], 0, 0, 0);
                    acc[i][j] = __builtin_amdgcn_mfma_f32_16x16x32_f16(al[i], bh[j], acc[i][j], 0, 0, 0);
                }
            }
        }
        __syncthreads();
    }

    // epilogue: C/D frag layout col = lane&15, row = (lane>>4)*4 + reg.
    const float inv = 1.0f / 65536.0f;  // undo 2^8 * 2^8 operand scaling (exact)
    #pragma unroll
    for (int i = 0; i < 4; i++) {
        int rrb = rb + wr * 64 + i * 16 + lk * 4;
        #pragma unroll
        for (int j = 0; j < 4; j++) {
            int cc = cb + wc * 64 + j * 16 + lrow;
            if (cc >= N_NODES) { continue; }
            #pragma unroll
            for (int q = 0; q < 4; q++) {
                int rr = rrb + q;
                if (rr >= N_NODES) { continue; }
                float v = fmaxf(acc[i][j][q] * inv, 0.f);
                S[(size_t)rr * N_NODES + cc] = v;
                S[(size_t)cc * N_NODES + rr] = v;  // mirror (bit-identical dot)
            }
        }
    }
}

// ---------------- radix-select top-30 per row, ties -> HIGHEST index ----------------
// v2: row kept in registers across both passes; threshold via wave-parallel
// suffix scans (no serial t==0 LDS chains); selection in registers when
// ncand <= 128 (typical ~30-80). cv/ci overlay the dead hist region.
__global__ __launch_bounds__(256) void topk_radix_kernel(float* __restrict__ S,
                                                         float* __restrict__ tv,
                                                         int* __restrict__ ti) {
    __shared__ int hist[NBINS];            // 16 KB; cv/ci overlay after threshold
    __shared__ int cntSh;
    __shared__ int thrSh;
    __shared__ float wv[4];
    __shared__ int wi[4];
    float* cv = (float*)hist;              // [0 .. CANDCAP)
    int*   ci = hist + CANDCAP;            // [CANDCAP .. 2*CANDCAP)
    int t = threadIdx.x;
    int r = blockIdx.x;
    float* row = S + (size_t)r * N_NODES;

    for (int b = t; b < NBINS; b += 256) { hist[b] = 0; }
    if (t == 0) { cntSh = 0; }
    __syncthreads();

    // one global read of the row, kept in registers for both passes
    float4 vv[10];
    int ok[10];
    #pragma unroll
    for (int u = 0; u < 10; u++) {
        int j4 = t + u * 256;
        ok[u] = j4 < NQ4;
        int jc = ok[u] ? j4 : (NQ4 - 1);
        vv[u] = *(const float4*)(row + 4 * jc);
    }

    // pass 1: histogram of positives
    #pragma unroll
    for (int u = 0; u < 10; u++) {
        if (!ok[u]) { continue; }
        float4 v = vv[u];
        if (v.x > 0.f) { atomicAdd(&hist[__float_as_uint(v.x) >> 18], 1); }
        if (v.y > 0.f) { atomicAdd(&hist[__float_as_uint(v.y) >> 18], 1); }
        if (v.z > 0.f) { atomicAdd(&hist[__float_as_uint(v.z) >> 18], 1); }
        if (v.w > 0.f) { atomicAdd(&hist[__float_as_uint(v.w) >> 18], 1); }
    }
    __syncthreads();

    // threshold: wave 0, fully wave-parallel (suffix scans + ballot)
    if (t < 64) {
        // chunk sum, rotated start to avoid same-bank reads across lanes
        int cs = 0;
        #pragma unroll
        for (int b = 0; b < 64; b++) { cs += hist[t * 64 + ((b + t) & 63)]; }
        // suffix sum across lanes: suf[t] = sum_{c>=t} cs[c]
        int suf = cs;
        #pragma unroll
        for (int off = 1; off < 64; off <<= 1) {
            int o = __shfl_down(suf, off, 64);
            suf += (t + off < 64) ? o : 0;
        }
        int npos = __shfl(suf, 0, 64);
        if (npos < KTOP) {
            if (t == 0) { thrSh = -1; }
        } else {
            unsigned long long m = __ballot(suf >= KTOP);      // contiguous low bits
            int cstar = __builtin_popcountll(m) - 1;           // largest c with suffix>=K
            int above = (cstar < 63) ? __shfl(suf, cstar + 1, 64) : 0;
            int bb = hist[cstar * 64 + t];                     // lane t -> bin t of chunk
            int bsuf = bb;
            #pragma unroll
            for (int off = 1; off < 64; off <<= 1) {
                int o = __shfl_down(bsuf, off, 64);
                bsuf += (t + off < 64) ? o : 0;
            }
            unsigned long long m2 = __ballot(above + bsuf >= KTOP);
            int bstar = __builtin_popcountll(m2) - 1;
            if (t == 0) { thrSh = cstar * 64 + bstar; }
        }
    }
    __syncthreads();
    int T = thrSh;

    if (T >= 0) {
        // pass 2: collect candidates from registers (no global re-read)
        #pragma unroll
        for (int u = 0; u < 10; u++) {
            if (!ok[u]) { continue; }
            float4 v = vv[u];
            int base = 4 * (t + u * 256);
            float vq[4];
            vq[0] = v.x; vq[1] = v.y; vq[2] = v.z; vq[3] = v.w;
            #pragma unroll
            for (int q = 0; q < 4; q++) {
                if (vq[q] > 0.f && (int)(__float_as_uint(vq[q]) >> 18) >= T) {
                    int p = atomicAdd(&cntSh, 1);
                    if (p < CANDCAP) {
                        cv[p] = vq[q];
                        ci[p] = base + q;
                    }
                }
            }
        }
    }
    __syncthreads();
    int ncand = cntSh;

    if (T < 0 || ncand > CANDCAP) {
        // exact fallback: block-wide iterative argmax over the global row
        for (int k = 0; k < KTOP; k++) {
            float bv = -1.f;
            int bi = -1;
            for (int j = t; j < N_NODES; j += 256) {
                float v = row[j];
                if (v >= bv) { bv = v; bi = j; }
            }
            for (int off = 32; off > 0; off >>= 1) {
                float ov = __shfl_down(bv, off, 64);
                int oi = __shfl_down(bi, off, 64);
                if (ov > bv || (ov == bv && oi > bi)) { bv = ov; bi = oi; }
            }
            if ((t & 63) == 0) { wv[t >> 6] = bv; wi[t >> 6] = bi; }
            __syncthreads();
            if (t == 0) {
                float fv = wv[0];
                int fi = wi[0];
                for (int q = 1; q < 4; q++) {
                    if (wv[q] > fv || (wv[q] == fv && wi[q] > fi)) { fv = wv[q]; fi = wi[q]; }
                }
                tv[r * KTOP + k] = fv;
                ti[r * KTOP + k] = fi;
                row[fi] = -1.f;
            }
            __syncthreads();
        }
        return;
    }

    if (ncand <= 128) {
        // register selection on wave 0: 2 candidates per lane, no LDS in loop
        if (t < 64) {
            float v0 = -2.f, v1 = -2.f;
            int i0 = -1, i1 = -1;
            if (t < ncand) { v0 = cv[t]; i0 = ci[t]; }
            if (t + 64 < ncand) { v1 = cv[t + 64]; i1 = ci[t + 64]; }
            for (int k = 0; k < KTOP; k++) {
                bool sel1 = (v1 > v0) || (v1 == v0 && i1 > i0);
                float bv = sel1 ? v1 : v0;
                int bi = sel1 ? i1 : i0;
                #pragma unroll
                for (int m = 32; m > 0; m >>= 1) {
                    float ov = __shfl_xor(bv, m, 64);
                    int oi = __shfl_xor(bi, m, 64);
                    if (ov > bv || (ov == bv && oi > bi)) { bv = ov; bi = oi; }
                }
                if (t == 0) {
                    tv[r * KTOP + k] = bv;
                    ti[r * KTOP + k] = bi;
                }
                if (i0 == bi) { v0 = -2.f; }
                if (i1 == bi) { v1 = -2.f; }
            }
        }
        return;
    }

    // selection (128 < ncand <= CANDCAP): wave 0, LDS loop; (value desc, index desc)
    if (t < 64) {
        for (int k = 0; k < KTOP; k++) {
            float bv = -2.f;
            int bi = -1;
            int bq = -1;
            for (int q = t; q < ncand; q += 64) {
                float v = cv[q];
                int idx = ci[q];
                if (v > bv || (v == bv && idx > bi)) { bv = v; bi = idx; bq = q; }
            }
            for (int m = 32; m > 0; m >>= 1) {
                float ov = __shfl_xor(bv, m, 64);
                int oi = __shfl_xor(bi, m, 64);
                int oq = __shfl_xor(bq, m, 64);
                if (ov > bv || (ov == bv && oi > bi)) { bv = ov; bi = oi; bq = oq; }
            }
            if (t == 0) {
                tv[r * KTOP + k] = bv;
                ti[r * KTOP + k] = bi;
                cv[bq] = -2.f;
            }
        }
    }
}

// ---------------- 400 MB zero fill (exact-bytes float4 streaming) ----------------
__global__ __launch_bounds__(256) void zero_fill(float4* __restrict__ p, unsigned int n4) {
    unsigned int i = blockIdx.x * 256u + threadIdx.x;
    unsigned int stride = gridDim.x * 256u;
    float4 z = {0.f, 0.f, 0.f, 0.f};
    for (; i < n4; i += stride) { p[i] = z; }
}

// ---------------- degree accumulation ----------------
__global__ __launch_bounds__(256) void degree_kernel(const float* __restrict__ tv,
                                                     const int* __restrict__ ti,
                                                     float* __restrict__ deg) {
    int e = blockIdx.x * 256 + threadIdx.x;
    if (e >= N_NODES * KTOP) { return; }
    int i = e / KTOP;
    int j = ti[e];
    float v = 0.5f * tv[e];
    atomicAdd(deg + i, v);
    atomicAdd(deg + j, v);
}

__global__ __launch_bounds__(256) void dis_kernel(const float* __restrict__ deg,
                                                  float* __restrict__ dis) {
    int i = blockIdx.x * 256 + threadIdx.x;
    if (i < N_NODES) {
        float d = deg[i];
        dis[i] = d > 0.f ? 1.f / sqrtf(fmaxf(d, 1e-8f)) : 0.f;
    }
}

// ---------------- CSR build ----------------
__global__ __launch_bounds__(256) void csr_build(const float* __restrict__ tv,
                                                 const int* __restrict__ ti,
                                                 const float* __restrict__ dis,
                                                 int* __restrict__ cnt,
                                                 int* __restrict__ nbr,
                                                 float* __restrict__ wgt) {
    int e = blockIdx.x * 256 + threadIdx.x;
    if (e >= N_NODES * KTOP) { return; }
    int i = e / KTOP;
    int j = ti[e];
    float v = tv[e];
    float vrev = 0.f;
    bool mutual = false;
    const int* tj = ti + (size_t)j * KTOP;
    const float* tvj = tv + (size_t)j * KTOP;
    for (int k = 0; k < KTOP; k++) {
        if (tj[k] == i) { vrev = tvj[k]; mutual = true; }
    }
    float w = 0.5f * (v + vrev) * dis[i] * dis[j];
    int p = atomicAdd(cnt + i, 1);
    if (p < CAP) {
        nbr[(size_t)i * CAP + p] = j;
        wgt[(size_t)i * CAP + p] = w;
    }
    if (!mutual) {
        int p2 = atomicAdd(cnt + j, 1);
        if (p2 < CAP) {
            nbr[(size_t)j * CAP + p2] = i;
            wgt[(size_t)j * CAP + p2] = w;
        }
    }
}

// ---------------- gather SpMM, 128 channels, relu fused ----------------
__global__ __launch_bounds__(256) void gather128(const int* __restrict__ cnt,
                                                 const int* __restrict__ nbr,
                                                 const float* __restrict__ wgt,
                                                 const float* __restrict__ T,
                                                 float* __restrict__ Y) {
    int node = blockIdx.x * 2 + (threadIdx.x >> 7);
    int c = threadIdx.x & 127;
    if (node >= N_NODES) { return; }
    int n = cnt[node];
    if (n > CAP) { n = CAP; }
    const int* nb = nbr + (size_t)node * CAP;
    const float* wg = wgt + (size_t)node * CAP;
    float acc = 0.f;
    for (int k = 0; k < n; k++) {
        acc = fmaf(wg[k], T[(size_t)nb[k] * 128 + c], acc);
    }
    Y[(size_t)node * 128 + c] = fmaxf(acc, 0.f);
}

// ---------------- gather SpMM, 16 channels ----------------
__global__ __launch_bounds__(256) void gather16(const int* __restrict__ cnt,
                                                const int* __restrict__ nbr,
                                                const float* __restrict__ wgt,
                                                const float* __restrict__ T,
                                                float* __restrict__ Y) {
    int node = blockIdx.x * 16 + (threadIdx.x >> 4);
    int c = threadIdx.x & 15;
    if (node >= N_NODES) { return; }
    int n = cnt[node];
    if (n > CAP) { n = CAP; }
    const int* nb = nbr + (size_t)node * CAP;
    const float* wg = wgt + (size_t)node * CAP;
    float acc = 0.f;
    for (int k = 0; k < n; k++) {
        acc = fmaf(wg[k], T[(size_t)nb[k] * 16 + c], acc);
    }
    Y[(size_t)node * 16 + c] = acc;
}

// ---------------- Adj scatter (dense output) ----------------
__global__ __launch_bounds__(256) void adj_scatter(const float* __restrict__ tv,
                                                   const int* __restrict__ ti,
                                                   const float* __restrict__ dis,
                                                   float* __restrict__ Adj) {
    int e = blockIdx.x * 256 + threadIdx.x;
    if (e >= N_NODES * KTOP) { return; }
    int i = e / KTOP;
    int j = ti[e];
    float v = tv[e];
    float vrev = 0.f;
    const int* tj = ti + (size_t)j * KTOP;
    const float* tvj = tv + (size_t)j * KTOP;
    for (int k = 0; k < KTOP; k++) {
        if (tj[k] == i) { vrev = tvj[k]; }
    }
    float w = 0.5f * (v + vrev) * dis[i] * dis[j];
    Adj[(size_t)i * N_NODES + j] = w;
    Adj[(size_t)j * N_NODES + i] = w;
}

extern "C" void kernel_launch(void* const* d_in, const int* in_sizes, int n_in,
                              void* d_out, int out_size, void* d_ws, size_t ws_size,
                              hipStream_t stream) {
    const float* features = (const float*)d_in[0];
    const float* x   = (const float*)d_in[1];
    const float* W1  = (const float*)d_in[2];
    const float* W2  = (const float*)d_in[3];
    const float* Wg1 = (const float*)d_in[4];
    const float* bg1 = (const float*)d_in[5];
    const float* Wg2 = (const float*)d_in[6];
    const float* bg2 = (const float*)d_in[7];

    float* ws = (float*)d_ws;
    float* hbuf = ws;                         // 2,560,000 f
    float* htmp = ws + 2560000;               // 2,560,000 f
    float* tv   = ws + 5120000;               // 300,000 f
    int*   ti   = (int*)(ws + 5420000);       // 300,000 i
    float* deg  = ws + 5720000;               // 10,000 f
    float* dis  = ws + 5730000;               // 10,000 f
    float* t2   = ws + 5740000;               // 160,000 f
    int*   cnt  = (int*)(ws + 5900000);       // 10,000 i
    float* t1   = hbuf;                       // reuse
    float* y1   = htmp;                       // reuse (after gemm_s consumed hi/lo)

    _Float16* Hhi = (_Float16*)(ws + 2560000);
    _Float16* Hlo = Hhi + 2560000;

    float* out_f = (float*)d_out;             // 160,000 f32
    float* Adj   = out_f + 160000;            // 1e8 f32 = 400 MB
    float* Sbuf  = Adj;                       // S until topk
    int*   nbr   = (int*)Adj;                 // CSR neighbors 82 MB
    float* wgt   = (float*)(Adj + (size_t)N_NODES * CAP);  // CSR weights 82 MB

    // ---- fp32 MLP chain ----
    dim3 g1(4, 79);
    gemm_rect<1, 0><<<g1, dim3(256), 0, stream>>>(
        features, W1, (const float*)nullptr, htmp, N_NODES, 256, 256);
    gemm_rect<0, 0><<<g1, dim3(256), 0, stream>>>(
        htmp, W2, (const float*)nullptr, hbuf, N_NODES, 256, 256);
    rownorm_np_kernel<<<dim3(N_NODES), dim3(256), 0, stream>>>(hbuf, Hhi, Hlo);

    // ---- S (triangle + mirror) via fp16-split MFMA, radix top-30 ----
    gemm_s_f16<<<dim3(79, 79), dim3(256), 0, stream>>>(Hhi, Hlo, Sbuf);
    topk_radix_kernel<<<dim3(N_NODES), dim3(256), 0, stream>>>(Sbuf, tv, ti);

    // ---- degrees + normalization ----
    hipMemsetAsync(deg, 0, N_NODES * sizeof(float), stream);
    int eblocks = (N_NODES * KTOP + 255) / 256;
    degree_kernel<<<dim3(eblocks), dim3(256), 0, stream>>>(tv, ti, deg);
    dis_kernel<<<dim3((N_NODES + 255) / 256), dim3(256), 0, stream>>>(deg, dis);

    // ---- CSR build in the (dead) S/Adj region ----
    hipMemsetAsync(cnt, 0, N_NODES * sizeof(int), stream);
    csr_build<<<dim3(eblocks), dim3(256), 0, stream>>>(tv, ti, dis, cnt, nbr, wgt);

    // ---- GCN layers via gather SpMM ----
    gemm_rect<0, 1><<<dim3(2, 79), dim3(256), 0, stream>>>(
        x, Wg1, bg1, t1, N_NODES, 128, 256);
    gather128<<<dim3(N_NODES / 2), dim3(256), 0, stream>>>(cnt, nbr, wgt, t1, y1);
    gemm_rect<0, 1><<<dim3(1, 79), dim3(256), 0, stream>>>(
        y1, Wg2, bg2, t2, N_NODES, 16, 128);
    gather16<<<dim3((N_NODES + 15) / 16), dim3(256), 0, stream>>>(cnt, nbr, wgt, t2, out_f);

    // ---- dense Adj output last (overwrites CSR region) ----
    zero_fill<<<dim3(2048), dim3(256), 0, stream>>>(
        (float4*)Adj, (unsigned int)((size_t)N_NODES * N_NODES / 4));
    adj_scatter<<<dim3(eblocks), dim3(256), 0, stream>>>(tv, ti, dis, Adj);
}

// Round 3
// 1239.473 us; speedup vs baseline: 1.3169x; 1.1643x over previous
//
#include <hip/hip_runtime.h>
#include <hip/hip_bf16.h>
#include <cstddef>

#define N_NODES 10000
#define KTOP 30
#define CAP 2048     // max CSR row length
#define NBINS 4096
#define CANDCAP 512
#define NQ4 (N_NODES / 4)   // 2500 float4 per row

typedef _Float16 f16x8 __attribute__((ext_vector_type(8)));
typedef float f32x4 __attribute__((ext_vector_type(4)));

// ---------------- fp32 GEMM: C[M,N] = op(A[M,K] @ B[K,N] + bias) ----------------
// (used for the two GCN layers only; MLP chain moved to MFMA)
template<int RELU, int BIAS>
__global__ __launch_bounds__(256) void gemm_rect(const float* __restrict__ A,
                                                 const float* __restrict__ B,
                                                 const float* __restrict__ bias,
                                                 float* __restrict__ C,
                                                 int M, int N, int K) {
    __shared__ float As[16][132];
    __shared__ float Bs[16][64];
    int t = threadIdx.x;
    int tx = t & 15;
    int ty = t >> 4;
    int m0 = blockIdx.y * 128;
    int n0 = blockIdx.x * 64;
    float acc[8][4];
    for (int r = 0; r < 8; r++) {
        for (int c = 0; c < 4; c++) { acc[r][c] = 0.f; }
    }
    for (int k0 = 0; k0 < K; k0 += 16) {
        for (int i = 0; i < 8; i++) {
            int idx = t + i * 256;
            int m = idx >> 4;
            int k = idx & 15;
            int gm = m0 + m;
            float v = 0.f;
            if (gm < M) { v = A[(size_t)gm * K + k0 + k]; }
            As[k][m] = v;
        }
        for (int i = 0; i < 4; i++) {
            int idx = t + i * 256;
            int k = idx >> 6;
            int n = idx & 63;
            int gn = n0 + n;
            float v = 0.f;
            if (gn < N) { v = B[(size_t)(k0 + k) * N + gn]; }
            Bs[k][n] = v;
        }
        __syncthreads();
        for (int kk = 0; kk < 16; kk++) {
            float a[8];
            float b[4];
            #pragma unroll
            for (int r = 0; r < 8; r++) { a[r] = As[kk][ty * 8 + r]; }
            #pragma unroll
            for (int c = 0; c < 4; c++) { b[c] = Bs[kk][tx * 4 + c]; }
            #pragma unroll
            for (int r = 0; r < 8; r++) {
                #pragma unroll
                for (int c = 0; c < 4; c++) {
                    acc[r][c] = fmaf(a[r], b[c], acc[r][c]);
                }
            }
        }
        __syncthreads();
    }
    for (int r = 0; r < 8; r++) {
        int gm = m0 + ty * 8 + r;
        if (gm >= M) { continue; }
        for (int c = 0; c < 4; c++) {
            int gn = n0 + tx * 4 + c;
            if (gn >= N) { continue; }
            float v = acc[r][c];
            if (BIAS) { v += bias[gn]; }
            if (RELU) { v = fmaxf(v, 0.f); }
            C[(size_t)gm * N + gn] = v;
        }
    }
}

// ---------------- fp16 2-way split helpers ----------------
// split(v): hi = f16(v*256), lo = f16(v*256 - hi). Scale 2^8 keeps values in
// the fp16 normal range; undone by 2^-16 after the hi/lo product GEMM.
__global__ __launch_bounds__(256) void split_rows(const float* __restrict__ src,
                                                  _Float16* __restrict__ hi,
                                                  _Float16* __restrict__ lo,
                                                  int n) {
    int i = blockIdx.x * 256 + threadIdx.x;
    if (i >= n) { return; }
    float v = src[i] * 256.0f;
    _Float16 h = (_Float16)v;
    hi[i] = h;
    lo[i] = (_Float16)(v - (float)h);
}

// W[k][n] (256x256) -> Wt[n][k] split (so MLP GEMM B-addressing == A-addressing)
__global__ __launch_bounds__(256) void splitWT(const float* __restrict__ W,
                                               _Float16* __restrict__ hi,
                                               _Float16* __restrict__ lo) {
    int n = blockIdx.x;
    int k = threadIdx.x;
    float v = W[k * 256 + n] * 256.0f;
    _Float16 h = (_Float16)v;
    hi[n * 256 + k] = h;
    lo[n * 256 + k] = (_Float16)(v - (float)h);
}

// ---------------- row normalize, numpy-pairwise-exact semantics ----------------
__global__ __launch_bounds__(256) void rownorm_np_kernel(const float* __restrict__ h,
                                                         _Float16* __restrict__ hhi,
                                                         _Float16* __restrict__ hlo) {
    __shared__ float row[256];
    __shared__ float denom_sh;
    int r = blockIdx.x;
    int t = threadIdx.x;
    const float* p = h + (size_t)r * 256;
    row[t] = p[t];
    __syncthreads();
    if (t == 0) {
        float res[2];
        for (int half = 0; half < 2; half++) {
            const float* a = row + half * 128;
            float rr[8];
            #pragma unroll
            for (int j = 0; j < 8; j++) {
                rr[j] = __fmul_rn(a[j], a[j]);
            }
            for (int i = 8; i < 128; i += 8) {
                #pragma unroll
                for (int j = 0; j < 8; j++) {
                    rr[j] = __fadd_rn(rr[j], __fmul_rn(a[i + j], a[i + j]));
                }
            }
            res[half] = __fadd_rn(
                __fadd_rn(__fadd_rn(rr[0], rr[1]), __fadd_rn(rr[2], rr[3])),
                __fadd_rn(__fadd_rn(rr[4], rr[5]), __fadd_rn(rr[6], rr[7])));
        }
        float tot = __fadd_rn(res[0], res[1]);
        denom_sh = __fadd_rn(__fsqrt_rn(tot), 1e-8f);
    }
    __syncthreads();
    float v = __fdiv_rn(row[t], denom_sh);
    float sc = v * 256.0f;                 // exact (power-of-2 scale)
    _Float16 hv = (_Float16)sc;            // RNE to fp16
    float rem = sc - (float)hv;            // exact (Sterbenz-range)
    hhi[(size_t)r * 256 + t] = hv;
    hlo[(size_t)r * 256 + t] = (_Float16)rem;
}

// ---------------- global_load_lds helper ----------------
__device__ __forceinline__ void gload16(const void* g, void* l) {
    __builtin_amdgcn_global_load_lds(
        (const __attribute__((address_space(1))) unsigned int*)g,
        (__attribute__((address_space(3))) unsigned int*)l, 16, 0, 0);
}

// ---------------- S tile GEMM via fp16-split MFMA ----------------
__global__ __launch_bounds__(256) void gemm_s_f16(const _Float16* __restrict__ hi,
                                                  const _Float16* __restrict__ lo,
                                                  float* __restrict__ S) {
    int rb = blockIdx.y * 128;
    int cb = blockIdx.x * 128;
    if (cb < rb) { return; }
    __shared__ __align__(16) unsigned short Hs[32768];  // 64 KB
    int t = threadIdx.x;
    int w = t >> 6;
    int lane = t & 63;
    int wr = w >> 1, wc = w & 1;          // wave -> 64x64 quadrant
    int lrow = lane & 15, lk = lane >> 4; // mfma A/B fragment mapping
    int lr8 = lane >> 3, ls8 = lane & 7;  // staging: 8 rows x 8 slots per 1KB chunk
    int koffb = ((ls8 ^ lr8) << 4);       // pre-swizzled 16B slot in global row

    f32x4 acc[4][4];
    #pragma unroll
    for (int i = 0; i < 4; i++) {
        #pragma unroll
        for (int j = 0; j < 4; j++) {
            f32x4 z = {0.f, 0.f, 0.f, 0.f};
            acc[i][j] = z;
        }
    }

    const char* hp = (const char*)hi;
    const char* lp = (const char*)lo;

    #pragma unroll 1
    for (int ks = 0; ks < 4; ks++) {
        int k0b = ks * 128;  // byte offset into a 512-B row
        #pragma unroll
        for (int tt = 0; tt < 4; tt++) {
            int c = w * 4 + tt;            // chunk 0..15, 8 rows each
            int rowloc = c * 8 + lr8;
            int na = rb + rowloc; if (na > N_NODES - 1) { na = N_NODES - 1; }
            int nb = cb + rowloc; if (nb > N_NODES - 1) { nb = N_NODES - 1; }
            size_t offA = (size_t)na * 512 + k0b + koffb;
            size_t offB = (size_t)nb * 512 + k0b + koffb;
            gload16(hp + offA, &Hs[0     + c * 512]);
            gload16(lp + offA, &Hs[8192  + c * 512]);
            gload16(hp + offB, &Hs[16384 + c * 512]);
            gload16(lp + offB, &Hs[24576 + c * 512]);
        }
        __builtin_amdgcn_s_waitcnt(0);
        __syncthreads();
        #pragma unroll 1
        for (int kk = 0; kk < 2; kk++) {
            f16x8 ah[4], al[4], bh[4], bl[4];
            #pragma unroll
            for (int i = 0; i < 4; i++) {
                int ar = wr * 64 + i * 16 + lrow;
                int br = wc * 64 + i * 16 + lrow;
                int ps = ((kk * 4 + lk) ^ (lrow & 7)) * 8;  // halves
                ah[i] = *(const f16x8*)&Hs[0     + ar * 64 + ps];
                al[i] = *(const f16x8*)&Hs[8192  + ar * 64 + ps];
                bh[i] = *(const f16x8*)&Hs[16384 + br * 64 + ps];
                bl[i] = *(const f16x8*)&Hs[24576 + br * 64 + ps];
            }
            #pragma unroll
            for (int i = 0; i < 4; i++) {
                #pragma unroll
                for (int j = 0; j < 4; j++) {
                    acc[i][j] = __builtin_amdgcn_mfma_f32_16x16x32_f16(ah[i], bh[j], acc[i][j], 0, 0, 0);
                    acc[i][j] = __builtin_amdgcn_mfma_f32_16x16x32_f16(ah[i], bl[j], acc[i][j], 0, 0, 0);
                    acc[i][j] = __builtin_amdgcn_mfma_f32_16x16x32_f16(al[i], bh[j], acc[i][j], 0, 0, 0);
                }
            }
        }
        __syncthreads();
    }

    // epilogue: C/D frag layout col = lane&15, row = (lane>>4)*4 + reg.
    const float inv = 1.0f / 65536.0f;  // undo 2^8 * 2^8 operand scaling (exact)
    #pragma unroll
    for (int i = 0; i < 4; i++) {
        int rrb = rb + wr * 64 + i * 16 + lk * 4;
        #pragma unroll
        for (int j = 0; j < 4; j++) {
            int cc = cb + wc * 64 + j * 16 + lrow;
            if (cc >= N_NODES) { continue; }
            #pragma unroll
            for (int q = 0; q < 4; q++) {
                int rr = rrb + q;
                if (rr >= N_NODES) { continue; }
                float v = fmaxf(acc[i][j][q] * inv, 0.f);
                S[(size_t)rr * N_NODES + cc] = v;
                S[(size_t)cc * N_NODES + rr] = v;  // mirror (bit-identical dot)
            }
        }
    }
}

// ---------------- MLP GEMM via fp16-split MFMA: C[M,256] = A[M,256] @ W ----------------
// A given as hi/lo (x2^8, row-major 256 halves/row); B given as Wt[n][k] hi/lo
// (x2^8) so B staging addressing is identical to A (NT layout).
// SPLIT_OUT=1: write relu(C) as hi/lo split (x2^8) for the next layer.
// SPLIT_OUT=0: write C as fp32 (unscaled).
template<int SPLIT_OUT>
__global__ __launch_bounds__(256) void gemm_mlp(const _Float16* __restrict__ ahi,
                                                const _Float16* __restrict__ alo,
                                                const _Float16* __restrict__ bhi,
                                                const _Float16* __restrict__ blo,
                                                _Float16* __restrict__ chi,
                                                _Float16* __restrict__ clo,
                                                float* __restrict__ cf) {
    int rb = blockIdx.y * 128;
    int cb = blockIdx.x * 128;
    __shared__ __align__(16) unsigned short Hs[32768];  // 64 KB
    int t = threadIdx.x;
    int w = t >> 6;
    int lane = t & 63;
    int wr = w >> 1, wc = w & 1;
    int lrow = lane & 15, lk = lane >> 4;
    int lr8 = lane >> 3, ls8 = lane & 7;
    int koffb = ((ls8 ^ lr8) << 4);

    f32x4 acc[4][4];
    #pragma unroll
    for (int i = 0; i < 4; i++) {
        #pragma unroll
        for (int j = 0; j < 4; j++) {
            f32x4 z = {0.f, 0.f, 0.f, 0.f};
            acc[i][j] = z;
        }
    }

    const char* ahp = (const char*)ahi;
    const char* alp = (const char*)alo;
    const char* bhp = (const char*)bhi;
    const char* blp = (const char*)blo;

    #pragma unroll 1
    for (int ks = 0; ks < 4; ks++) {
        int k0b = ks * 128;
        #pragma unroll
        for (int tt = 0; tt < 4; tt++) {
            int c = w * 4 + tt;
            int rowloc = c * 8 + lr8;
            int na = rb + rowloc; if (na > N_NODES - 1) { na = N_NODES - 1; }
            int nb = cb + rowloc;              // Wt rows: 0..255, always valid
            size_t offA = (size_t)na * 512 + k0b + koffb;
            size_t offB = (size_t)nb * 512 + k0b + koffb;
            gload16(ahp + offA, &Hs[0     + c * 512]);
            gload16(alp + offA, &Hs[8192  + c * 512]);
            gload16(bhp + offB, &Hs[16384 + c * 512]);
            gload16(blp + offB, &Hs[24576 + c * 512]);
        }
        __builtin_amdgcn_s_waitcnt(0);
        __syncthreads();
        #pragma unroll 1
        for (int kk = 0; kk < 2; kk++) {
            f16x8 ah[4], al[4], bh[4], bl[4];
            #pragma unroll
            for (int i = 0; i < 4; i++) {
                int ar = wr * 64 + i * 16 + lrow;
                int br = wc * 64 + i * 16 + lrow;
                int ps = ((kk * 4 + lk) ^ (lrow & 7)) * 8;
                ah[i] = *(const f16x8*)&Hs[0     + ar * 64 + ps];
                al[i] = *(const f16x8*)&Hs[8192  + ar * 64 + ps];
                bh[i] = *(const f16x8*)&Hs[16384 + br * 64 + ps];
                bl[i] = *(const f16x8*)&Hs[24576 + br * 64 + ps];
            }
            #pragma unroll
            for (int i = 0; i < 4; i++) {
                #pragma unroll
                for (int j = 0; j < 4; j++) {
                    acc[i][j] = __builtin_amdgcn_mfma_f32_16x16x32_f16(ah[i], bh[j], acc[i][j], 0, 0, 0);
                    acc[i][j] = __builtin_amdgcn_mfma_f32_16x16x32_f16(ah[i], bl[j], acc[i][j], 0, 0, 0);
                    acc[i][j] = __builtin_amdgcn_mfma_f32_16x16x32_f16(al[i], bh[j], acc[i][j], 0, 0, 0);
                }
            }
        }
        __syncthreads();
    }

    const float inv = 1.0f / 65536.0f;
    #pragma unroll
    for (int i = 0; i < 4; i++) {
        int rrb = rb + wr * 64 + i * 16 + lk * 4;
        #pragma unroll
        for (int j = 0; j < 4; j++) {
            int cc = cb + wc * 64 + j * 16 + lrow;   // < 256 always
            #pragma unroll
            for (int q = 0; q < 4; q++) {
                int rr = rrb + q;
                if (rr >= N_NODES) { continue; }
                if (SPLIT_OUT) {
                    // relu then re-split at x2^8: acc*2^-16*256 = acc/256
                    float sv = fmaxf(acc[i][j][q], 0.f) * (1.0f / 256.0f);
                    _Float16 hv = (_Float16)sv;
                    chi[(size_t)rr * 256 + cc] = hv;
                    clo[(size_t)rr * 256 + cc] = (_Float16)(sv - (float)hv);
                } else {
                    cf[(size_t)rr * 256 + cc] = acc[i][j][q] * inv;
                }
            }
        }
    }
}

// ---------------- radix-select top-30 per row, ties -> HIGHEST index ----------------
// v3: additionally ZEROES its own S row (fused Adj-zero) in the non-fallback
// paths; fallback zeroes at the end. Row held in registers for both passes.
__global__ __launch_bounds__(256) void topk_radix_kernel(float* __restrict__ S,
                                                         float* __restrict__ tv,
                                                         int* __restrict__ ti) {
    __shared__ int hist[NBINS];            // 16 KB; cv/ci overlay after threshold
    __shared__ int cntSh;
    __shared__ int thrSh;
    __shared__ float wv[4];
    __shared__ int wi[4];
    float* cv = (float*)hist;              // [0 .. CANDCAP)
    int*   ci = hist + CANDCAP;            // [CANDCAP .. 2*CANDCAP)
    int t = threadIdx.x;
    int r = blockIdx.x;
    float* row = S + (size_t)r * N_NODES;

    for (int b = t; b < NBINS; b += 256) { hist[b] = 0; }
    if (t == 0) { cntSh = 0; }
    __syncthreads();

    // one global read of the row, kept in registers for both passes
    float4 vv[10];
    int ok[10];
    #pragma unroll
    for (int u = 0; u < 10; u++) {
        int j4 = t + u * 256;
        ok[u] = j4 < NQ4;
        int jc = ok[u] ? j4 : (NQ4 - 1);
        vv[u] = *(const float4*)(row + 4 * jc);
    }

    // pass 1: histogram of positives
    #pragma unroll
    for (int u = 0; u < 10; u++) {
        if (!ok[u]) { continue; }
        float4 v = vv[u];
        if (v.x > 0.f) { atomicAdd(&hist[__float_as_uint(v.x) >> 18], 1); }
        if (v.y > 0.f) { atomicAdd(&hist[__float_as_uint(v.y) >> 18], 1); }
        if (v.z > 0.f) { atomicAdd(&hist[__float_as_uint(v.z) >> 18], 1); }
        if (v.w > 0.f) { atomicAdd(&hist[__float_as_uint(v.w) >> 18], 1); }
    }
    __syncthreads();

    // threshold: wave 0, fully wave-parallel (suffix scans + ballot)
    if (t < 64) {
        int cs = 0;
        #pragma unroll
        for (int b = 0; b < 64; b++) { cs += hist[t * 64 + ((b + t) & 63)]; }
        int suf = cs;
        #pragma unroll
        for (int off = 1; off < 64; off <<= 1) {
            int o = __shfl_down(suf, off, 64);
            suf += (t + off < 64) ? o : 0;
        }
        int npos = __shfl(suf, 0, 64);
        if (npos < KTOP) {
            if (t == 0) { thrSh = -1; }
        } else {
            unsigned long long m = __ballot(suf >= KTOP);
            int cstar = __builtin_popcountll(m) - 1;
            int above = (cstar < 63) ? __shfl(suf, cstar + 1, 64) : 0;
            int bb = hist[cstar * 64 + t];
            int bsuf = bb;
            #pragma unroll
            for (int off = 1; off < 64; off <<= 1) {
                int o = __shfl_down(bsuf, off, 64);
                bsuf += (t + off < 64) ? o : 0;
            }
            unsigned long long m2 = __ballot(above + bsuf >= KTOP);
            int bstar = __builtin_popcountll(m2) - 1;
            if (t == 0) { thrSh = cstar * 64 + bstar; }
        }
    }
    __syncthreads();
    int T = thrSh;

    if (T >= 0) {
        // pass 2: collect candidates from registers (no global re-read)
        #pragma unroll
        for (int u = 0; u < 10; u++) {
            if (!ok[u]) { continue; }
            float4 v = vv[u];
            int base = 4 * (t + u * 256);
            float vq[4];
            vq[0] = v.x; vq[1] = v.y; vq[2] = v.z; vq[3] = v.w;
            #pragma unroll
            for (int q = 0; q < 4; q++) {
                if (vq[q] > 0.f && (int)(__float_as_uint(vq[q]) >> 18) >= T) {
                    int p = atomicAdd(&cntSh, 1);
                    if (p < CANDCAP) {
                        cv[p] = vq[q];
                        ci[p] = base + q;
                    }
                }
            }
        }
    }
    __syncthreads();
    int ncand = cntSh;
    bool fb = (T < 0 || ncand > CANDCAP);

    if (!fb) {
        // fused Adj-zero: wipe own row (stores drain in selection's shadow)
        float4 z = {0.f, 0.f, 0.f, 0.f};
        #pragma unroll
        for (int u = 0; u < 10; u++) {
            if (ok[u]) { *(float4*)(row + 4 * (t + u * 256)) = z; }
        }
    }

    if (fb) {
        // exact fallback: block-wide iterative argmax over the global row
        for (int k = 0; k < KTOP; k++) {
            float bv = -1.f;
            int bi = -1;
            for (int j = t; j < N_NODES; j += 256) {
                float v = row[j];
                if (v >= bv) { bv = v; bi = j; }
            }
            for (int off = 32; off > 0; off >>= 1) {
                float ov = __shfl_down(bv, off, 64);
                int oi = __shfl_down(bi, off, 64);
                if (ov > bv || (ov == bv && oi > bi)) { bv = ov; bi = oi; }
            }
            if ((t & 63) == 0) { wv[t >> 6] = bv; wi[t >> 6] = bi; }
            __syncthreads();
            if (t == 0) {
                float fv = wv[0];
                int fi = wi[0];
                for (int q = 1; q < 4; q++) {
                    if (wv[q] > fv || (wv[q] == fv && wi[q] > fi)) { fv = wv[q]; fi = wi[q]; }
                }
                tv[r * KTOP + k] = fv;
                ti[r * KTOP + k] = fi;
                row[fi] = -1.f;
            }
            __syncthreads();
        }
        // zero row after fallback selection
        float4 z = {0.f, 0.f, 0.f, 0.f};
        for (int u = 0; u < 10; u++) {
            int j4 = t + u * 256;
            if (j4 < NQ4) { *(float4*)(row + 4 * j4) = z; }
        }
        return;
    }

    if (ncand <= 128) {
        // register selection on wave 0: 2 candidates per lane, no LDS in loop
        if (t < 64) {
            float v0 = -2.f, v1 = -2.f;
            int i0 = -1, i1 = -1;
            if (t < ncand) { v0 = cv[t]; i0 = ci[t]; }
            if (t + 64 < ncand) { v1 = cv[t + 64]; i1 = ci[t + 64]; }
            for (int k = 0; k < KTOP; k++) {
                bool sel1 = (v1 > v0) || (v1 == v0 && i1 > i0);
                float bv = sel1 ? v1 : v0;
                int bi = sel1 ? i1 : i0;
                #pragma unroll
                for (int m = 32; m > 0; m >>= 1) {
                    float ov = __shfl_xor(bv, m, 64);
                    int oi = __shfl_xor(bi, m, 64);
                    if (ov > bv || (ov == bv && oi > bi)) { bv = ov; bi = oi; }
                }
                if (t == 0) {
                    tv[r * KTOP + k] = bv;
                    ti[r * KTOP + k] = bi;
                }
                if (i0 == bi) { v0 = -2.f; }
                if (i1 == bi) { v1 = -2.f; }
            }
        }
        return;
    }

    // selection (128 < ncand <= CANDCAP): wave 0, LDS loop
    if (t < 64) {
        for (int k = 0; k < KTOP; k++) {
            float bv = -2.f;
            int bi = -1;
            int bq = -1;
            for (int q = t; q < ncand; q += 64) {
                float v = cv[q];
                int idx = ci[q];
                if (v > bv || (v == bv && idx > bi)) { bv = v; bi = idx; bq = q; }
            }
            for (int m = 32; m > 0; m >>= 1) {
                float ov = __shfl_xor(bv, m, 64);
                int oi = __shfl_xor(bi, m, 64);
                int oq = __shfl_xor(bq, m, 64);
                if (ov > bv || (ov == bv && oi > bi)) { bv = ov; bi = oi; bq = oq; }
            }
            if (t == 0) {
                tv[r * KTOP + k] = bv;
                ti[r * KTOP + k] = bi;
                cv[bq] = -2.f;
            }
        }
    }
}

// ---------------- zero fill (fallback path only: CSR region re-zero) ----------------
__global__ __launch_bounds__(256) void zero_fill(float4* __restrict__ p, unsigned int n4) {
    unsigned int i = blockIdx.x * 256u + threadIdx.x;
    unsigned int stride = gridDim.x * 256u;
    float4 z = {0.f, 0.f, 0.f, 0.f};
    for (; i < n4; i += stride) { p[i] = z; }
}

// ---------------- degree accumulation ----------------
__global__ __launch_bounds__(256) void degree_kernel(const float* __restrict__ tv,
                                                     const int* __restrict__ ti,
                                                     float* __restrict__ deg) {
    int e = blockIdx.x * 256 + threadIdx.x;
    if (e >= N_NODES * KTOP) { return; }
    int i = e / KTOP;
    int j = ti[e];
    float v = 0.5f * tv[e];
    atomicAdd(deg + i, v);
    atomicAdd(deg + j, v);
}

__global__ __launch_bounds__(256) void dis_kernel(const float* __restrict__ deg,
                                                  float* __restrict__ dis) {
    int i = blockIdx.x * 256 + threadIdx.x;
    if (i < N_NODES) {
        float d = deg[i];
        dis[i] = d > 0.f ? 1.f / sqrtf(fmaxf(d, 1e-8f)) : 0.f;
    }
}

// ---------------- CSR build ----------------
__global__ __launch_bounds__(256) void csr_build(const float* __restrict__ tv,
                                                 const int* __restrict__ ti,
                                                 const float* __restrict__ dis,
                                                 int* __restrict__ cnt,
                                                 int* __restrict__ nbr,
                                                 float* __restrict__ wgt) {
    int e = blockIdx.x * 256 + threadIdx.x;
    if (e >= N_NODES * KTOP) { return; }
    int i = e / KTOP;
    int j = ti[e];
    float v = tv[e];
    float vrev = 0.f;
    bool mutual = false;
    const int* tj = ti + (size_t)j * KTOP;
    const float* tvj = tv + (size_t)j * KTOP;
    for (int k = 0; k < KTOP; k++) {
        if (tj[k] == i) { vrev = tvj[k]; mutual = true; }
    }
    float w = 0.5f * (v + vrev) * dis[i] * dis[j];
    int p = atomicAdd(cnt + i, 1);
    if (p < CAP) {
        nbr[(size_t)i * CAP + p] = j;
        wgt[(size_t)i * CAP + p] = w;
    }
    if (!mutual) {
        int p2 = atomicAdd(cnt + j, 1);
        if (p2 < CAP) {
            nbr[(size_t)j * CAP + p2] = i;
            wgt[(size_t)j * CAP + p2] = w;
        }
    }
}

// ---------------- gather SpMM, 128 channels, relu fused (4x ILP) ----------------
__global__ __launch_bounds__(256) void gather128(const int* __restrict__ cnt,
                                                 const int* __restrict__ nbr,
                                                 const float* __restrict__ wgt,
                                                 const float* __restrict__ T,
                                                 float* __restrict__ Y) {
    int node = blockIdx.x * 2 + (threadIdx.x >> 7);
    int c = threadIdx.x & 127;
    if (node >= N_NODES) { return; }
    int n = cnt[node];
    if (n > CAP) { n = CAP; }
    const int* nb = nbr + (size_t)node * CAP;
    const float* wg = wgt + (size_t)node * CAP;
    float a0 = 0.f, a1 = 0.f, a2 = 0.f, a3 = 0.f;
    int k = 0;
    for (; k + 4 <= n; k += 4) {
        int4 j = *(const int4*)(nb + k);
        float4 w = *(const float4*)(wg + k);
        float t0 = T[(size_t)j.x * 128 + c];
        float t1 = T[(size_t)j.y * 128 + c];
        float t2 = T[(size_t)j.z * 128 + c];
        float t3 = T[(size_t)j.w * 128 + c];
        a0 = fmaf(w.x, t0, a0);
        a1 = fmaf(w.y, t1, a1);
        a2 = fmaf(w.z, t2, a2);
        a3 = fmaf(w.w, t3, a3);
    }
    for (; k < n; k++) { a0 = fmaf(wg[k], T[(size_t)nb[k] * 128 + c], a0); }
    float acc = (a0 + a1) + (a2 + a3);
    Y[(size_t)node * 128 + c] = fmaxf(acc, 0.f);
}

// ---------------- gather SpMM, 16 channels (4x ILP) ----------------
__global__ __launch_bounds__(256) void gather16(const int* __restrict__ cnt,
                                                const int* __restrict__ nbr,
                                                const float* __restrict__ wgt,
                                                const float* __restrict__ T,
                                                float* __restrict__ Y) {
    int node = blockIdx.x * 16 + (threadIdx.x >> 4);
    int c = threadIdx.x & 15;
    if (node >= N_NODES) { return; }
    int n = cnt[node];
    if (n > CAP) { n = CAP; }
    const int* nb = nbr + (size_t)node * CAP;
    const float* wg = wgt + (size_t)node * CAP;
    float a0 = 0.f, a1 = 0.f, a2 = 0.f, a3 = 0.f;
    int k = 0;
    for (; k + 4 <= n; k += 4) {
        int4 j = *(const int4*)(nb + k);
        float4 w = *(const float4*)(wg + k);
        float t0 = T[(size_t)j.x * 16 + c];
        float t1 = T[(size_t)j.y * 16 + c];
        float t2 = T[(size_t)j.z * 16 + c];
        float t3 = T[(size_t)j.w * 16 + c];
        a0 = fmaf(w.x, t0, a0);
        a1 = fmaf(w.y, t1, a1);
        a2 = fmaf(w.z, t2, a2);
        a3 = fmaf(w.w, t3, a3);
    }
    for (; k < n; k++) { a0 = fmaf(wg[k], T[(size_t)nb[k] * 16 + c], a0); }
    Y[(size_t)node * 16 + c] = (a0 + a1) + (a2 + a3);
}

// ---------------- Adj scatter (dense output) ----------------
__global__ __launch_bounds__(256) void adj_scatter(const float* __restrict__ tv,
                                                   const int* __restrict__ ti,
                                                   const float* __restrict__ dis,
                                                   float* __restrict__ Adj) {
    int e = blockIdx.x * 256 + threadIdx.x;
    if (e >= N_NODES * KTOP) { return; }
    int i = e / KTOP;
    int j = ti[e];
    float v = tv[e];
    float vrev = 0.f;
    const int* tj = ti + (size_t)j * KTOP;
    const float* tvj = tv + (size_t)j * KTOP;
    for (int k = 0; k < KTOP; k++) {
        if (tj[k] == i) { vrev = tvj[k]; }
    }
    float w = 0.5f * (v + vrev) * dis[i] * dis[j];
    Adj[(size_t)i * N_NODES + j] = w;
    Adj[(size_t)j * N_NODES + i] = w;
}

extern "C" void kernel_launch(void* const* d_in, const int* in_sizes, int n_in,
                              void* d_out, int out_size, void* d_ws, size_t ws_size,
                              hipStream_t stream) {
    const float* features = (const float*)d_in[0];
    const float* x   = (const float*)d_in[1];
    const float* W1  = (const float*)d_in[2];
    const float* W2  = (const float*)d_in[3];
    const float* Wg1 = (const float*)d_in[4];
    const float* bg1 = (const float*)d_in[5];
    const float* Wg2 = (const float*)d_in[6];
    const float* bg2 = (const float*)d_in[7];

    float* ws = (float*)d_ws;
    float* hbuf = ws;                         // [0, 2,560,000) f: h fp32, later t1
    float* tv   = ws + 5120000;               // 300,000 f
    int*   ti   = (int*)(ws + 5420000);       // 300,000 i
    float* deg  = ws + 5720000;               // 10,000 f
    float* dis  = ws + 5730000;               // 10,000 f
    float* t2   = ws + 5740000;               // 160,000 f (W-splits live here early)
    int*   cnt  = (int*)(ws + 5900000);       // 10,000 i
    float* t1   = hbuf;                       // reuse
    float* y1   = ws + 2560000;               // htmp region reuse

    // fp16 split buffers (sequenced overlays):
    //  fsp (features split) in hbuf region: dead after gemm_mlp1; hbuf (h) written by gemm_mlp2.
    _Float16* fsphi = (_Float16*)ws;                    // 2.56M halves
    _Float16* fsplo = fsphi + 2560000;
    //  h1sp (relu(h1) split) in htmp region: dead after gemm_mlp2; then Hhi/Hlo reuse it.
    _Float16* h1hi = (_Float16*)(ws + 2560000);
    _Float16* h1lo = h1hi + 2560000;
    _Float16* Hhi  = (_Float16*)(ws + 2560000);         // rownorm out (after h1sp dead)
    _Float16* Hlo  = Hhi + 2560000;
    //  W transposes+splits in t2 region (dead before t2 is written)
    _Float16* W1thi = (_Float16*)(ws + 5740000);        // 65,536 halves
    _Float16* W1tlo = W1thi + 65536;
    _Float16* W2thi = W1thi + 131072;
    _Float16* W2tlo = W1thi + 196608;                   // ends at float-off 5,838,  within t2

    float* out_f = (float*)d_out;             // 160,000 f32
    float* Adj   = out_f + 160000;            // 1e8 f32 = 400 MB
    float* Sbuf  = Adj;                       // S until topk (topk zeroes it)

    // CSR placement: workspace if it fits, else alias Adj (needs re-zero later)
    size_t csr_off = 5910000;                                  // floats
    size_t csr_need = (csr_off + (size_t)N_NODES * CAP * 2) * sizeof(float);
    bool csr_in_ws = ws_size >= csr_need;
    int*   nbr = csr_in_ws ? (int*)(ws + csr_off) : (int*)Adj;
    float* wgt = csr_in_ws ? (float*)(ws + csr_off + (size_t)N_NODES * CAP)
                           : (float*)(Adj + (size_t)N_NODES * CAP);

    // ---- MLP chain via fp16-split MFMA ----
    split_rows<<<dim3(10000), dim3(256), 0, stream>>>(features, fsphi, fsplo, 2560000);
    splitWT<<<dim3(256), dim3(256), 0, stream>>>(W1, W1thi, W1tlo);
    splitWT<<<dim3(256), dim3(256), 0, stream>>>(W2, W2thi, W2tlo);
    gemm_mlp<1><<<dim3(2, 79), dim3(256), 0, stream>>>(
        fsphi, fsplo, W1thi, W1tlo, h1hi, h1lo, (float*)nullptr);
    gemm_mlp<0><<<dim3(2, 79), dim3(256), 0, stream>>>(
        h1hi, h1lo, W2thi, W2tlo, (_Float16*)nullptr, (_Float16*)nullptr, hbuf);
    rownorm_np_kernel<<<dim3(N_NODES), dim3(256), 0, stream>>>(hbuf, Hhi, Hlo);

    // ---- S (triangle + mirror) via fp16-split MFMA; topk selects + zeroes S ----
    gemm_s_f16<<<dim3(79, 79), dim3(256), 0, stream>>>(Hhi, Hlo, Sbuf);
    topk_radix_kernel<<<dim3(N_NODES), dim3(256), 0, stream>>>(Sbuf, tv, ti);

    // ---- degrees + normalization ----
    hipMemsetAsync(deg, 0, N_NODES * sizeof(float), stream);
    int eblocks = (N_NODES * KTOP + 255) / 256;
    degree_kernel<<<dim3(eblocks), dim3(256), 0, stream>>>(tv, ti, deg);
    dis_kernel<<<dim3((N_NODES + 255) / 256), dim3(256), 0, stream>>>(deg, dis);

    // ---- CSR build ----
    hipMemsetAsync(cnt, 0, N_NODES * sizeof(int), stream);
    csr_build<<<dim3(eblocks), dim3(256), 0, stream>>>(tv, ti, dis, cnt, nbr, wgt);

    // ---- GCN layers via gather SpMM ----
    gemm_rect<0, 1><<<dim3(2, 79), dim3(256), 0, stream>>>(
        x, Wg1, bg1, t1, N_NODES, 128, 256);
    gather128<<<dim3(N_NODES / 2), dim3(256), 0, stream>>>(cnt, nbr, wgt, t1, y1);
    gemm_rect<0, 1><<<dim3(1, 79), dim3(256), 0, stream>>>(
        y1, Wg2, bg2, t2, N_NODES, 16, 128);
    gather16<<<dim3((N_NODES + 15) / 16), dim3(256), 0, stream>>>(cnt, nbr, wgt, t2, out_f);

    // ---- dense Adj output: S already zeroed by topk; only re-zero if CSR aliased Adj ----
    if (!csr_in_ws) {
        zero_fill<<<dim3(2048), dim3(256), 0, stream>>>(
            (float4*)Adj, (unsigned int)((size_t)N_NODES * CAP * 2 / 4));
    }
    adj_scatter<<<dim3(eblocks), dim3(256), 0, stream>>>(tv, ti, dis, Adj);
}

// Round 4
// 1091.672 us; speedup vs baseline: 1.4952x; 1.1354x over previous
//
#include <hip/hip_runtime.h>
#include <hip/hip_bf16.h>
#include <cstddef>

#define N_NODES 10000
#define KTOP 30
#define CAP 2048     // max CSR row length
#define NBINS 4096
#define CANDCAP 512
#define NQ4 (N_NODES / 4)   // 2500 float4 per row

typedef _Float16 f16x8 __attribute__((ext_vector_type(8)));
typedef float f32x4 __attribute__((ext_vector_type(4)));

// ---------------- fp16 2-way split helpers ----------------
// split(v): hi = f16(v*256), lo = f16(v*256 - hi). Scale 2^8 keeps values in
// the fp16 normal range; undone by 2^-16 after the hi/lo product GEMM.
__global__ __launch_bounds__(256) void split_rows(const float* __restrict__ src,
                                                  _Float16* __restrict__ hi,
                                                  _Float16* __restrict__ lo,
                                                  int n) {
    int i = blockIdx.x * 256 + threadIdx.x;
    if (i >= n) { return; }
    float v = src[i] * 256.0f;
    _Float16 h = (_Float16)v;
    hi[i] = h;
    lo[i] = (_Float16)(v - (float)h);
}

// W[k][n] (256 x N) -> Wt[n][k] split (so GEMM B-addressing == A-addressing)
__global__ __launch_bounds__(256) void splitWT(const float* __restrict__ W,
                                               _Float16* __restrict__ hi,
                                               _Float16* __restrict__ lo,
                                               int N) {
    int n = blockIdx.x;
    int k = threadIdx.x;
    float v = W[k * N + n] * 256.0f;
    _Float16 h = (_Float16)v;
    hi[n * 256 + k] = h;
    lo[n * 256 + k] = (_Float16)(v - (float)h);
}

// ---------------- row normalize, numpy-pairwise-exact semantics ----------------
// 16-lane parallel version of the original serial chain. The 8 rr[j] chains and
// the 2 halves are independent in the original; the cross-lane combine uses the
// exact same pairwise tree (IEEE fadd is commutative-exact, so shfl_xor pairs
// produce bit-identical sums).
__global__ __launch_bounds__(256) void rownorm_np_kernel(const float* __restrict__ h,
                                                         _Float16* __restrict__ hhi,
                                                         _Float16* __restrict__ hlo) {
    __shared__ float row[256];
    __shared__ float denom_sh;
    int r = blockIdx.x;
    int t = threadIdx.x;
    const float* p = h + (size_t)r * 256;
    row[t] = p[t];
    __syncthreads();
    if (t < 16) {
        int half = t >> 3;
        int j = t & 7;
        const float* a = row + half * 128 + j;
        float rr = __fmul_rn(a[0], a[0]);
        #pragma unroll
        for (int i = 1; i < 16; i++) {
            rr = __fadd_rn(rr, __fmul_rn(a[i * 8], a[i * 8]));
        }
        // tree: ((rr0+rr1)+(rr2+rr3))+((rr4+rr5)+(rr6+rr7)) per half, then res0+res1
        #pragma unroll
        for (int off = 1; off <= 8; off <<= 1) {
            rr = __fadd_rn(rr, __shfl_xor(rr, off, 64));
        }
        if (t == 0) { denom_sh = __fadd_rn(__fsqrt_rn(rr), 1e-8f); }
    }
    __syncthreads();
    float v = __fdiv_rn(row[t], denom_sh);
    float sc = v * 256.0f;                 // exact (power-of-2 scale)
    _Float16 hv = (_Float16)sc;            // RNE to fp16
    float rem = sc - (float)hv;            // exact (Sterbenz-range)
    hhi[(size_t)r * 256 + t] = hv;
    hlo[(size_t)r * 256 + t] = (_Float16)rem;
}

// ---------------- global_load_lds helper ----------------
__device__ __forceinline__ void gload16(const void* g, void* l) {
    __builtin_amdgcn_global_load_lds(
        (const __attribute__((address_space(1))) unsigned int*)g,
        (__attribute__((address_space(3))) unsigned int*)l, 16, 0, 0);
}

// ---------------- S tile GEMM via fp16-split MFMA, double-buffered pipeline ----------------
// v2: 8 K-steps of 32 halves, 2 x 32 KB LDS buffers, raw s_barrier + counted
// s_waitcnt vmcnt(8) so next-stage global_load_lds stays in flight across the
// barrier (no vmcnt(0) drain in the main loop).
// LDS row layout (128 B = 8 x 16B slots): logical slots 0-3 = hi k-slots,
// 4-7 = lo k-slots, stored at phys p = s ^ (row&7). The same involution is
// applied on the global source (staging) and on the ds_read side.
// Race proof: leading barrier is preceded by each wave's vmcnt(8) (own stage-s
// loads done; <=8 outstanding = stage-s+1 only) => at barrier exit ALL waves'
// stage-s LDS writes are complete. Trailing barrier ensures all reads of
// buf[s&1] finish before any wave issues STAGE(s+2) (which overwrites buf[s&1]).
__global__ __launch_bounds__(256) void gemm_s_f16(const _Float16* __restrict__ hi,
                                                  const _Float16* __restrict__ lo,
                                                  float* __restrict__ S) {
    int rb = blockIdx.y * 128;
    int cb = blockIdx.x * 128;
    if (cb < rb) { return; }
    __shared__ __align__(16) unsigned short Hs[2][16384];  // 2 x 32 KB (A at 0, B at 8192)
    int t = threadIdx.x;
    int w = t >> 6;
    int lane = t & 63;
    int wr = w >> 1, wc = w & 1;          // wave -> 64x64 quadrant
    int lrow = lane & 15, lk = lane >> 4; // mfma A/B fragment mapping
    int lr8 = lane >> 3, ls8 = lane & 7;  // staging: 8 rows x 8 phys slots per 1KB chunk

    // staging: 32 chunks/stage (A:0-15, B:16-31), 8 chunks per wave.
    int slog = ls8 ^ lr8;                  // logical slot this lane sources
    const char* srcp = (slog < 4) ? (const char*)hi : (const char*)lo;
    int koff = (slog & 3) * 16;            // 16B k-slot within the stage's 64B range
    int cbase = w * 8;

    f32x4 acc[4][4];
    #pragma unroll
    for (int i = 0; i < 4; i++) {
        #pragma unroll
        for (int j = 0; j < 4; j++) {
            f32x4 z = {0.f, 0.f, 0.f, 0.f};
            acc[i][j] = z;
        }
    }

    auto STAGE = [&](int sidx, int b) {
        int kb = sidx * 64;                // byte offset of stage's k-range (32 halves)
        #pragma unroll
        for (int tt = 0; tt < 8; tt++) {
            int c = cbase + tt;            // chunk 0..31
            int rl = ((c & 15) << 3) + lr8;
            int node = ((c >> 4) ? cb : rb) + rl;
            if (node > N_NODES - 1) { node = N_NODES - 1; }
            gload16(srcp + (size_t)node * 512 + kb + koff, &Hs[b][c << 9]);
        }
    };

    STAGE(0, 0);
    #pragma unroll 1
    for (int s = 0; s < 8; s++) {
        int b = s & 1;
        if (s < 7) { STAGE(s + 1, b ^ 1); }
        __builtin_amdgcn_sched_barrier(0);
        if (s < 7) { asm volatile("s_waitcnt vmcnt(8)" ::: "memory"); }
        else       { asm volatile("s_waitcnt vmcnt(0)" ::: "memory"); }
        __builtin_amdgcn_s_barrier();
        __builtin_amdgcn_sched_barrier(0);
        f16x8 ah[4], al[4], bh[4], bl[4];
        #pragma unroll
        for (int i = 0; i < 4; i++) {
            int ar = wr * 64 + i * 16 + lrow;
            int br = wc * 64 + i * 16 + lrow;
            int ra7 = ar & 7, rb7 = br & 7;
            ah[i] = *(const f16x8*)&Hs[b][ar * 64 + ((lk ^ ra7) << 3)];
            al[i] = *(const f16x8*)&Hs[b][ar * 64 + (((lk + 4) ^ ra7) << 3)];
            bh[i] = *(const f16x8*)&Hs[b][8192 + br * 64 + ((lk ^ rb7) << 3)];
            bl[i] = *(const f16x8*)&Hs[b][8192 + br * 64 + (((lk + 4) ^ rb7) << 3)];
        }
        #pragma unroll
        for (int i = 0; i < 4; i++) {
            #pragma unroll
            for (int j = 0; j < 4; j++) {
                acc[i][j] = __builtin_amdgcn_mfma_f32_16x16x32_f16(ah[i], bh[j], acc[i][j], 0, 0, 0);
                acc[i][j] = __builtin_amdgcn_mfma_f32_16x16x32_f16(ah[i], bl[j], acc[i][j], 0, 0, 0);
                acc[i][j] = __builtin_amdgcn_mfma_f32_16x16x32_f16(al[i], bh[j], acc[i][j], 0, 0, 0);
            }
        }
        __builtin_amdgcn_sched_barrier(0);
        __builtin_amdgcn_s_barrier();
    }

    // epilogue: C/D frag layout col = lane&15, row = (lane>>4)*4 + reg.
    const float inv = 1.0f / 65536.0f;  // undo 2^8 * 2^8 operand scaling (exact)
    #pragma unroll
    for (int i = 0; i < 4; i++) {
        int rrb = rb + wr * 64 + i * 16 + lk * 4;
        #pragma unroll
        for (int j = 0; j < 4; j++) {
            int cc = cb + wc * 64 + j * 16 + lrow;
            if (cc >= N_NODES) { continue; }
            #pragma unroll
            for (int q = 0; q < 4; q++) {
                int rr = rrb + q;
                if (rr >= N_NODES) { continue; }
                float v = fmaxf(acc[i][j][q] * inv, 0.f);
                S[(size_t)rr * N_NODES + cc] = v;
                S[(size_t)cc * N_NODES + rr] = v;  // mirror (bit-identical dot)
            }
        }
    }
}

// ---------------- generic 128-tile GEMM via fp16-split MFMA ----------------
// C[M, on] = A[M,256] @ Wt^T (+bias). A as hi/lo (x2^8); B as Wt[n][256] hi/lo
// (x2^8). MODE 0: fp32 out (stride on, optional bias). MODE 1: relu + re-split
// out (x2^8, stride 256).
template<int MODE>
__global__ __launch_bounds__(256) void gemm_mlp(const _Float16* __restrict__ ahi,
                                                const _Float16* __restrict__ alo,
                                                const _Float16* __restrict__ bhi,
                                                const _Float16* __restrict__ blo,
                                                _Float16* __restrict__ chi,
                                                _Float16* __restrict__ clo,
                                                float* __restrict__ cf,
                                                const float* __restrict__ bias,
                                                int on) {
    int rb = blockIdx.y * 128;
    int cb = blockIdx.x * 128;
    __shared__ __align__(16) unsigned short Hs[32768];  // 64 KB
    int t = threadIdx.x;
    int w = t >> 6;
    int lane = t & 63;
    int wr = w >> 1, wc = w & 1;
    int lrow = lane & 15, lk = lane >> 4;
    int lr8 = lane >> 3, ls8 = lane & 7;
    int koffb = ((ls8 ^ lr8) << 4);

    f32x4 acc[4][4];
    #pragma unroll
    for (int i = 0; i < 4; i++) {
        #pragma unroll
        for (int j = 0; j < 4; j++) {
            f32x4 z = {0.f, 0.f, 0.f, 0.f};
            acc[i][j] = z;
        }
    }

    const char* ahp = (const char*)ahi;
    const char* alp = (const char*)alo;
    const char* bhp = (const char*)bhi;
    const char* blp = (const char*)blo;

    #pragma unroll 1
    for (int ks = 0; ks < 4; ks++) {
        int k0b = ks * 128;
        #pragma unroll
        for (int tt = 0; tt < 4; tt++) {
            int c = w * 4 + tt;
            int rowloc = c * 8 + lr8;
            int na = rb + rowloc; if (na > N_NODES - 1) { na = N_NODES - 1; }
            int nb = cb + rowloc;              // Wt rows always valid
            size_t offA = (size_t)na * 512 + k0b + koffb;
            size_t offB = (size_t)nb * 512 + k0b + koffb;
            gload16(ahp + offA, &Hs[0     + c * 512]);
            gload16(alp + offA, &Hs[8192  + c * 512]);
            gload16(bhp + offB, &Hs[16384 + c * 512]);
            gload16(blp + offB, &Hs[24576 + c * 512]);
        }
        __builtin_amdgcn_s_waitcnt(0);
        __syncthreads();
        #pragma unroll 1
        for (int kk = 0; kk < 2; kk++) {
            f16x8 ah[4], al[4], bh[4], bl[4];
            #pragma unroll
            for (int i = 0; i < 4; i++) {
                int ar = wr * 64 + i * 16 + lrow;
                int br = wc * 64 + i * 16 + lrow;
                int ps = ((kk * 4 + lk) ^ (lrow & 7)) * 8;
                ah[i] = *(const f16x8*)&Hs[0     + ar * 64 + ps];
                al[i] = *(const f16x8*)&Hs[8192  + ar * 64 + ps];
                bh[i] = *(const f16x8*)&Hs[16384 + br * 64 + ps];
                bl[i] = *(const f16x8*)&Hs[24576 + br * 64 + ps];
            }
            #pragma unroll
            for (int i = 0; i < 4; i++) {
                #pragma unroll
                for (int j = 0; j < 4; j++) {
                    acc[i][j] = __builtin_amdgcn_mfma_f32_16x16x32_f16(ah[i], bh[j], acc[i][j], 0, 0, 0);
                    acc[i][j] = __builtin_amdgcn_mfma_f32_16x16x32_f16(ah[i], bl[j], acc[i][j], 0, 0, 0);
                    acc[i][j] = __builtin_amdgcn_mfma_f32_16x16x32_f16(al[i], bh[j], acc[i][j], 0, 0, 0);
                }
            }
        }
        __syncthreads();
    }

    const float inv = 1.0f / 65536.0f;
    #pragma unroll
    for (int i = 0; i < 4; i++) {
        int rrb = rb + wr * 64 + i * 16 + lk * 4;
        #pragma unroll
        for (int j = 0; j < 4; j++) {
            int cc = cb + wc * 64 + j * 16 + lrow;
            if (cc >= on && MODE == 0) { continue; }
            #pragma unroll
            for (int q = 0; q < 4; q++) {
                int rr = rrb + q;
                if (rr >= N_NODES) { continue; }
                if (MODE == 1) {
                    // relu then re-split at x2^8: acc*2^-16*256 = acc/256
                    float sv = fmaxf(acc[i][j][q], 0.f) * (1.0f / 256.0f);
                    _Float16 hv = (_Float16)sv;
                    chi[(size_t)rr * 256 + cc] = hv;
                    clo[(size_t)rr * 256 + cc] = (_Float16)(sv - (float)hv);
                } else {
                    float v = acc[i][j][q] * inv;
                    if (bias != nullptr) { v += bias[cc]; }
                    cf[(size_t)rr * on + cc] = v;
                }
            }
        }
    }
}

// ---------------- radix-select top-30 per row, ties -> HIGHEST index ----------------
// v4: fused Adj-zero (wipes own S row) + fused degree accumulation (deg must be
// pre-zeroed). Row held in registers for both passes; wave-parallel scans.
__global__ __launch_bounds__(256) void topk_radix_kernel(float* __restrict__ S,
                                                         float* __restrict__ tv,
                                                         int* __restrict__ ti,
                                                         float* __restrict__ deg) {
    __shared__ int hist[NBINS];            // 16 KB; cv/ci overlay after threshold
    __shared__ int cntSh;
    __shared__ int thrSh;
    __shared__ float wv[4];
    __shared__ int wi[4];
    float* cv = (float*)hist;              // [0 .. CANDCAP)
    int*   ci = hist + CANDCAP;            // [CANDCAP .. 2*CANDCAP)
    int t = threadIdx.x;
    int r = blockIdx.x;
    float* row = S + (size_t)r * N_NODES;

    for (int b = t; b < NBINS; b += 256) { hist[b] = 0; }
    if (t == 0) { cntSh = 0; }
    __syncthreads();

    // one global read of the row, kept in registers for both passes
    float4 vv[10];
    int ok[10];
    #pragma unroll
    for (int u = 0; u < 10; u++) {
        int j4 = t + u * 256;
        ok[u] = j4 < NQ4;
        int jc = ok[u] ? j4 : (NQ4 - 1);
        vv[u] = *(const float4*)(row + 4 * jc);
    }

    // pass 1: histogram of positives
    #pragma unroll
    for (int u = 0; u < 10; u++) {
        if (!ok[u]) { continue; }
        float4 v = vv[u];
        if (v.x > 0.f) { atomicAdd(&hist[__float_as_uint(v.x) >> 18], 1); }
        if (v.y > 0.f) { atomicAdd(&hist[__float_as_uint(v.y) >> 18], 1); }
        if (v.z > 0.f) { atomicAdd(&hist[__float_as_uint(v.z) >> 18], 1); }
        if (v.w > 0.f) { atomicAdd(&hist[__float_as_uint(v.w) >> 18], 1); }
    }
    __syncthreads();

    // threshold: wave 0, fully wave-parallel (suffix scans + ballot)
    if (t < 64) {
        int cs = 0;
        #pragma unroll
        for (int b = 0; b < 64; b++) { cs += hist[t * 64 + ((b + t) & 63)]; }
        int suf = cs;
        #pragma unroll
        for (int off = 1; off < 64; off <<= 1) {
            int o = __shfl_down(suf, off, 64);
            suf += (t + off < 64) ? o : 0;
        }
        int npos = __shfl(suf, 0, 64);
        if (npos < KTOP) {
            if (t == 0) { thrSh = -1; }
        } else {
            unsigned long long m = __ballot(suf >= KTOP);
            int cstar = __builtin_popcountll(m) - 1;
            int above = (cstar < 63) ? __shfl(suf, cstar + 1, 64) : 0;
            int bb = hist[cstar * 64 + t];
            int bsuf = bb;
            #pragma unroll
            for (int off = 1; off < 64; off <<= 1) {
                int o = __shfl_down(bsuf, off, 64);
                bsuf += (t + off < 64) ? o : 0;
            }
            unsigned long long m2 = __ballot(above + bsuf >= KTOP);
            int bstar = __builtin_popcountll(m2) - 1;
            if (t == 0) { thrSh = cstar * 64 + bstar; }
        }
    }
    __syncthreads();
    int T = thrSh;

    if (T >= 0) {
        // pass 2: collect candidates from registers (no global re-read)
        #pragma unroll
        for (int u = 0; u < 10; u++) {
            if (!ok[u]) { continue; }
            float4 v = vv[u];
            int base = 4 * (t + u * 256);
            float vq[4];
            vq[0] = v.x; vq[1] = v.y; vq[2] = v.z; vq[3] = v.w;
            #pragma unroll
            for (int q = 0; q < 4; q++) {
                if (vq[q] > 0.f && (int)(__float_as_uint(vq[q]) >> 18) >= T) {
                    int p = atomicAdd(&cntSh, 1);
                    if (p < CANDCAP) {
                        cv[p] = vq[q];
                        ci[p] = base + q;
                    }
                }
            }
        }
    }
    __syncthreads();
    int ncand = cntSh;
    bool fb = (T < 0 || ncand > CANDCAP);

    if (!fb) {
        // fused Adj-zero: wipe own row (stores drain in selection's shadow)
        float4 z = {0.f, 0.f, 0.f, 0.f};
        #pragma unroll
        for (int u = 0; u < 10; u++) {
            if (ok[u]) { *(float4*)(row + 4 * (t + u * 256)) = z; }
        }
    }

    if (fb) {
        // exact fallback: block-wide iterative argmax over the global row
        float rs = 0.f;
        for (int k = 0; k < KTOP; k++) {
            float bv = -1.f;
            int bi = -1;
            for (int j = t; j < N_NODES; j += 256) {
                float v = row[j];
                if (v >= bv) { bv = v; bi = j; }
            }
            for (int off = 32; off > 0; off >>= 1) {
                float ov = __shfl_down(bv, off, 64);
                int oi = __shfl_down(bi, off, 64);
                if (ov > bv || (ov == bv && oi > bi)) { bv = ov; bi = oi; }
            }
            if ((t & 63) == 0) { wv[t >> 6] = bv; wi[t >> 6] = bi; }
            __syncthreads();
            if (t == 0) {
                float fv = wv[0];
                int fi = wi[0];
                for (int q = 1; q < 4; q++) {
                    if (wv[q] > fv || (wv[q] == fv && wi[q] > fi)) { fv = wv[q]; fi = wi[q]; }
                }
                tv[r * KTOP + k] = fv;
                ti[r * KTOP + k] = fi;
                atomicAdd(deg + fi, 0.5f * fv);
                rs += fv;
                row[fi] = -1.f;
            }
            __syncthreads();
        }
        if (t == 0) { atomicAdd(deg + r, 0.5f * rs); }
        // zero row after fallback selection
        float4 z = {0.f, 0.f, 0.f, 0.f};
        for (int u = 0; u < 10; u++) {
            int j4 = t + u * 256;
            if (j4 < NQ4) { *(float4*)(row + 4 * j4) = z; }
        }
        return;
    }

    if (ncand <= 128) {
        // register selection on wave 0: 2 candidates per lane, no LDS in loop
        if (t < 64) {
            float v0 = -2.f, v1 = -2.f;
            int i0 = -1, i1 = -1;
            if (t < ncand) { v0 = cv[t]; i0 = ci[t]; }
            if (t + 64 < ncand) { v1 = cv[t + 64]; i1 = ci[t + 64]; }
            float rs = 0.f;
            for (int k = 0; k < KTOP; k++) {
                bool sel1 = (v1 > v0) || (v1 == v0 && i1 > i0);
                float bv = sel1 ? v1 : v0;
                int bi = sel1 ? i1 : i0;
                #pragma unroll
                for (int m = 32; m > 0; m >>= 1) {
                    float ov = __shfl_xor(bv, m, 64);
                    int oi = __shfl_xor(bi, m, 64);
                    if (ov > bv || (ov == bv && oi > bi)) { bv = ov; bi = oi; }
                }
                if (t == 0) {
                    tv[r * KTOP + k] = bv;
                    ti[r * KTOP + k] = bi;
                    atomicAdd(deg + bi, 0.5f * bv);
                    rs += bv;
                }
                if (i0 == bi) { v0 = -2.f; }
                if (i1 == bi) { v1 = -2.f; }
            }
            if (t == 0) { atomicAdd(deg + r, 0.5f * rs); }
        }
        return;
    }

    // selection (128 < ncand <= CANDCAP): wave 0, LDS loop
    if (t < 64) {
        float rs = 0.f;
        for (int k = 0; k < KTOP; k++) {
            float bv = -2.f;
            int bi = -1;
            int bq = -1;
            for (int q = t; q < ncand; q += 64) {
                float v = cv[q];
                int idx = ci[q];
                if (v > bv || (v == bv && idx > bi)) { bv = v; bi = idx; bq = q; }
            }
            for (int m = 32; m > 0; m >>= 1) {
                float ov = __shfl_xor(bv, m, 64);
                int oi = __shfl_xor(bi, m, 64);
                int oq = __shfl_xor(bq, m, 64);
                if (ov > bv || (ov == bv && oi > bi)) { bv = ov; bi = oi; bq = oq; }
            }
            if (t == 0) {
                tv[r * KTOP + k] = bv;
                ti[r * KTOP + k] = bi;
                atomicAdd(deg + bi, 0.5f * bv);
                rs += bv;
                cv[bq] = -2.f;
            }
        }
        if (t == 0) { atomicAdd(deg + r, 0.5f * rs); }
    }
}

// ---------------- zero fill (fallback path only: CSR region re-zero) ----------------
__global__ __launch_bounds__(256) void zero_fill(float4* __restrict__ p, unsigned int n4) {
    unsigned int i = blockIdx.x * 256u + threadIdx.x;
    unsigned int stride = gridDim.x * 256u;
    float4 z = {0.f, 0.f, 0.f, 0.f};
    for (; i < n4; i += stride) { p[i] = z; }
}

__global__ __launch_bounds__(256) void dis_kernel(const float* __restrict__ deg,
                                                  float* __restrict__ dis) {
    int i = blockIdx.x * 256 + threadIdx.x;
    if (i < N_NODES) {
        float d = deg[i];
        dis[i] = d > 0.f ? 1.f / sqrtf(fmaxf(d, 1e-8f)) : 0.f;
    }
}

// ---------------- CSR build (+ optional fused dense Adj scatter) ----------------
template<int WRITE_ADJ>
__global__ __launch_bounds__(256) void csr_adj(const float* __restrict__ tv,
                                               const int* __restrict__ ti,
                                               const float* __restrict__ dis,
                                               int* __restrict__ cnt,
                                               int* __restrict__ nbr,
                                               float* __restrict__ wgt,
                                               float* __restrict__ Adj) {
    int e = blockIdx.x * 256 + threadIdx.x;
    if (e >= N_NODES * KTOP) { return; }
    int i = e / KTOP;
    int j = ti[e];
    float v = tv[e];
    float vrev = 0.f;
    bool mutual = false;
    const int* tj = ti + (size_t)j * KTOP;
    const float* tvj = tv + (size_t)j * KTOP;
    for (int k = 0; k < KTOP; k++) {
        if (tj[k] == i) { vrev = tvj[k]; mutual = true; }
    }
    float w = 0.5f * (v + vrev) * dis[i] * dis[j];
    int p = atomicAdd(cnt + i, 1);
    if (p < CAP) {
        nbr[(size_t)i * CAP + p] = j;
        wgt[(size_t)i * CAP + p] = w;
    }
    if (!mutual) {
        int p2 = atomicAdd(cnt + j, 1);
        if (p2 < CAP) {
            nbr[(size_t)j * CAP + p2] = i;
            wgt[(size_t)j * CAP + p2] = w;
        }
    }
    if (WRITE_ADJ) {
        Adj[(size_t)i * N_NODES + j] = w;
        Adj[(size_t)j * N_NODES + i] = w;
    }
}

// ---------------- Adj scatter (fallback path only) ----------------
__global__ __launch_bounds__(256) void adj_scatter(const float* __restrict__ tv,
                                                   const int* __restrict__ ti,
                                                   const float* __restrict__ dis,
                                                   float* __restrict__ Adj) {
    int e = blockIdx.x * 256 + threadIdx.x;
    if (e >= N_NODES * KTOP) { return; }
    int i = e / KTOP;
    int j = ti[e];
    float v = tv[e];
    float vrev = 0.f;
    const int* tj = ti + (size_t)j * KTOP;
    const float* tvj = tv + (size_t)j * KTOP;
    for (int k = 0; k < KTOP; k++) {
        if (tj[k] == i) { vrev = tvj[k]; }
    }
    float w = 0.5f * (v + vrev) * dis[i] * dis[j];
    Adj[(size_t)i * N_NODES + j] = w;
    Adj[(size_t)j * N_NODES + i] = w;
}

// ---------------- gather SpMM, 128 channels, relu fused (4x ILP) ----------------
__global__ __launch_bounds__(256) void gather128(const int* __restrict__ cnt,
                                                 const int* __restrict__ nbr,
                                                 const float* __restrict__ wgt,
                                                 const float* __restrict__ T,
                                                 float* __restrict__ Y) {
    int node = blockIdx.x * 2 + (threadIdx.x >> 7);
    int c = threadIdx.x & 127;
    if (node >= N_NODES) { return; }
    int n = cnt[node];
    if (n > CAP) { n = CAP; }
    const int* nb = nbr + (size_t)node * CAP;
    const float* wg = wgt + (size_t)node * CAP;
    float a0 = 0.f, a1 = 0.f, a2 = 0.f, a3 = 0.f;
    int k = 0;
    for (; k + 4 <= n; k += 4) {
        int4 j = *(const int4*)(nb + k);
        float4 w = *(const float4*)(wg + k);
        float t0 = T[(size_t)j.x * 128 + c];
        float t1 = T[(size_t)j.y * 128 + c];
        float t2 = T[(size_t)j.z * 128 + c];
        float t3 = T[(size_t)j.w * 128 + c];
        a0 = fmaf(w.x, t0, a0);
        a1 = fmaf(w.y, t1, a1);
        a2 = fmaf(w.z, t2, a2);
        a3 = fmaf(w.w, t3, a3);
    }
    for (; k < n; k++) { a0 = fmaf(wg[k], T[(size_t)nb[k] * 128 + c], a0); }
    float acc = (a0 + a1) + (a2 + a3);
    Y[(size_t)node * 128 + c] = fmaxf(acc, 0.f);
}

// ---------------- y1[M,128] @ Wg2[128,16] + bg2 -> t2[M,16] ----------------
__global__ __launch_bounds__(256) void gemm16(const float* __restrict__ y1,
                                              const float* __restrict__ Wg2,
                                              const float* __restrict__ bg2,
                                              float* __restrict__ out) {
    __shared__ float Ws[2048];          // Wg2 [128][16]
    __shared__ float Ys[16 * 132];      // 16 rows x 128 (+4 pad)
    int t = threadIdx.x;
    int n0 = blockIdx.x * 16;
    for (int i = t; i < 2048; i += 256) {
        Ws[i] = Wg2[i];
        int rr = i >> 7, cc = i & 127;
        int node = n0 + rr;
        if (node > N_NODES - 1) { node = N_NODES - 1; }
        Ys[rr * 132 + cc] = y1[(size_t)node * 128 + cc];
    }
    __syncthreads();
    int nn = t >> 4;
    int c = t & 15;
    int node = n0 + nn;
    if (node >= N_NODES) { return; }
    const float* yr = Ys + nn * 132;
    float acc = 0.f;
    #pragma unroll 4
    for (int k = 0; k < 128; k++) {
        acc = fmaf(yr[k], Ws[k * 16 + c], acc);
    }
    out[(size_t)node * 16 + c] = acc + bg2[c];
}

// ---------------- gather SpMM, 16 channels (4x ILP) ----------------
__global__ __launch_bounds__(256) void gather16(const int* __restrict__ cnt,
                                                const int* __restrict__ nbr,
                                                const float* __restrict__ wgt,
                                                const float* __restrict__ T,
                                                float* __restrict__ Y) {
    int node = blockIdx.x * 16 + (threadIdx.x >> 4);
    int c = threadIdx.x & 15;
    if (node >= N_NODES) { return; }
    int n = cnt[node];
    if (n > CAP) { n = CAP; }
    const int* nb = nbr + (size_t)node * CAP;
    const float* wg = wgt + (size_t)node * CAP;
    float a0 = 0.f, a1 = 0.f, a2 = 0.f, a3 = 0.f;
    int k = 0;
    for (; k + 4 <= n; k += 4) {
        int4 j = *(const int4*)(nb + k);
        float4 w = *(const float4*)(wg + k);
        float t0 = T[(size_t)j.x * 16 + c];
        float t1 = T[(size_t)j.y * 16 + c];
        float t2 = T[(size_t)j.z * 16 + c];
        float t3 = T[(size_t)j.w * 16 + c];
        a0 = fmaf(w.x, t0, a0);
        a1 = fmaf(w.y, t1, a1);
        a2 = fmaf(w.z, t2, a2);
        a3 = fmaf(w.w, t3, a3);
    }
    for (; k < n; k++) { a0 = fmaf(wg[k], T[(size_t)nb[k] * 16 + c], a0); }
    Y[(size_t)node * 16 + c] = (a0 + a1) + (a2 + a3);
}

extern "C" void kernel_launch(void* const* d_in, const int* in_sizes, int n_in,
                              void* d_out, int out_size, void* d_ws, size_t ws_size,
                              hipStream_t stream) {
    const float* features = (const float*)d_in[0];
    const float* x   = (const float*)d_in[1];
    const float* W1  = (const float*)d_in[2];
    const float* W2  = (const float*)d_in[3];
    const float* Wg1 = (const float*)d_in[4];
    const float* bg1 = (const float*)d_in[5];
    const float* Wg2 = (const float*)d_in[6];
    const float* bg2 = (const float*)d_in[7];

    float* ws = (float*)d_ws;
    // region A [0, 2.56M) floats: fsp split -> hbuf (h fp32) -> xsp split
    // region B [2.56M, 5.12M) floats: h1sp split -> Hhi/Hlo -> t1 | y1
    float* hbuf = ws;
    float* tv   = ws + 5120000;               // 300,000 f
    int*   ti   = (int*)(ws + 5420000);       // 300,000 i
    float* deg  = ws + 5720000;               // 10,000 f
    float* dis  = ws + 5730000;               // 10,000 f
    float* t2   = ws + 5740000;               // 160,000 f (W-splits live here early)
    int*   cnt  = (int*)(ws + 5900000);       // 10,000 i
    float* t1   = ws + 2560000;               // Hhi region, after gemm_s dead
    float* y1   = ws + 3840000;               // Hlo region, after gemm_s dead

    _Float16* fsphi = (_Float16*)ws;
    _Float16* fsplo = fsphi + 2560000;
    _Float16* xsphi = (_Float16*)ws;                    // after hbuf dead (post rownorm)
    _Float16* xsplo = xsphi + 2560000;
    _Float16* h1hi = (_Float16*)(ws + 2560000);
    _Float16* h1lo = h1hi + 2560000;
    _Float16* Hhi  = (_Float16*)(ws + 2560000);
    _Float16* Hlo  = Hhi + 2560000;
    _Float16* W1thi = (_Float16*)(ws + 5740000);        // 65,536 halves each
    _Float16* W1tlo = W1thi + 65536;
    _Float16* W2thi = W1thi + 131072;
    _Float16* W2tlo = W1thi + 196608;
    _Float16* Wg1thi = (_Float16*)(ws + 5740000);       // reuse after MLP chain (128x256)
    _Float16* Wg1tlo = Wg1thi + 32768;

    float* out_f = (float*)d_out;             // 160,000 f32
    float* Adj   = out_f + 160000;            // 1e8 f32 = 400 MB
    float* Sbuf  = Adj;                       // S until topk (topk zeroes it)

    // CSR placement: workspace if it fits, else alias Adj (needs re-zero later)
    size_t csr_off = 5910000;                                  // floats
    size_t csr_need = (csr_off + (size_t)N_NODES * CAP * 2) * sizeof(float);
    bool csr_in_ws = ws_size >= csr_need;
    int*   nbr = csr_in_ws ? (int*)(ws + csr_off) : (int*)Adj;
    float* wgt = csr_in_ws ? (float*)(ws + csr_off + (size_t)N_NODES * CAP)
                           : (float*)(Adj + (size_t)N_NODES * CAP);

    // ---- MLP chain via fp16-split MFMA ----
    split_rows<<<dim3(10000), dim3(256), 0, stream>>>(features, fsphi, fsplo, 2560000);
    splitWT<<<dim3(256), dim3(256), 0, stream>>>(W1, W1thi, W1tlo, 256);
    splitWT<<<dim3(256), dim3(256), 0, stream>>>(W2, W2thi, W2tlo, 256);
    gemm_mlp<1><<<dim3(2, 79), dim3(256), 0, stream>>>(
        fsphi, fsplo, W1thi, W1tlo, h1hi, h1lo, (float*)nullptr, (const float*)nullptr, 256);
    gemm_mlp<0><<<dim3(2, 79), dim3(256), 0, stream>>>(
        h1hi, h1lo, W2thi, W2tlo, (_Float16*)nullptr, (_Float16*)nullptr, hbuf,
        (const float*)nullptr, 256);
    rownorm_np_kernel<<<dim3(N_NODES), dim3(256), 0, stream>>>(hbuf, Hhi, Hlo);

    // ---- x split + Wg1 split (hbuf dead; W1t/W2t dead) ----
    split_rows<<<dim3(10000), dim3(256), 0, stream>>>(x, xsphi, xsplo, 2560000);
    splitWT<<<dim3(128), dim3(256), 0, stream>>>(Wg1, Wg1thi, Wg1tlo, 128);

    // ---- S (triangle + mirror), pipelined MFMA; topk selects + zeroes S + degrees ----
    gemm_s_f16<<<dim3(79, 79), dim3(256), 0, stream>>>(Hhi, Hlo, Sbuf);
    hipMemsetAsync(deg, 0, N_NODES * sizeof(float), stream);
    topk_radix_kernel<<<dim3(N_NODES), dim3(256), 0, stream>>>(Sbuf, tv, ti, deg);

    // ---- GCN layer-1 GEMM (t1 over dead Hhi region) ----
    gemm_mlp<0><<<dim3(1, 79), dim3(256), 0, stream>>>(
        xsphi, xsplo, Wg1thi, Wg1tlo, (_Float16*)nullptr, (_Float16*)nullptr, t1, bg1, 128);

    dis_kernel<<<dim3((N_NODES + 255) / 256), dim3(256), 0, stream>>>(deg, dis);

    // ---- CSR build (+ fused Adj scatter when CSR lives in ws) ----
    hipMemsetAsync(cnt, 0, N_NODES * sizeof(int), stream);
    int eblocks = (N_NODES * KTOP + 255) / 256;
    if (csr_in_ws) {
        csr_adj<1><<<dim3(eblocks), dim3(256), 0, stream>>>(tv, ti, dis, cnt, nbr, wgt, Adj);
    } else {
        csr_adj<0><<<dim3(eblocks), dim3(256), 0, stream>>>(tv, ti, dis, cnt, nbr, wgt, Adj);
    }

    // ---- GCN layers via gather SpMM ----
    gather128<<<dim3(N_NODES / 2), dim3(256), 0, stream>>>(cnt, nbr, wgt, t1, y1);
    gemm16<<<dim3(625), dim3(256), 0, stream>>>(y1, Wg2, bg2, t2);
    gather16<<<dim3((N_NODES + 15) / 16), dim3(256), 0, stream>>>(cnt, nbr, wgt, t2, out_f);

    // ---- fallback: CSR aliased Adj -> re-zero that region and scatter dense Adj ----
    if (!csr_in_ws) {
        zero_fill<<<dim3(2048), dim3(256), 0, stream>>>(
            (float4*)Adj, (unsigned int)((size_t)N_NODES * CAP * 2 / 4));
        adj_scatter<<<dim3(eblocks), dim3(256), 0, stream>>>(tv, ti, dis, Adj);
    }
}